// Round 7
// baseline (295.451 us; speedup 1.0000x reference)
//
#include <hip/hip_runtime.h>
#include <math.h>

#define NTHREADS 256
#define TOUT 118            // outputs per block
#define NP 120              // beta positions per block (TOUT+2)
#define WROWS 30            // conv positions per wave (NP/4)
#define X1S 40              // x1 row stride (u16), cols 20..31 zeroed
#define T3S 88              // t3 row stride (u16): 176B = 11x16B (odd) -> 2-way banks
#define NDIF 128            // real dif entries, base P0-5 (NP+8)
#define NDIFP 144           // padded difh array (conv1-MFMA reads up to 141)
#define NUU 130             // uu, base J0-4 (TOUT+12)
#define WREG (WROWS * T3S)  // 2640 u16 per wave-private region (x1 34x40 -> t3 30x88)
#define LOG2E 1.44269504f
#define LN2   0.69314718f

// weight-fragment table in d_ws: 44 frags x 64 lanes x 8 bf16 (16 B)
#define F2_BASE 0           // conv2: 15 frags (mt 0..2, s 0..4)
#define F3_BASE 15          // conv3: 10 frags (mt 0..4, s 0..1)
#define F4_BASE 25          // conv4: 9  frags (mt 0..2, s 0..2)
#define F5_BASE 34          // conv5: 8  frags (mt 0..1, s 0..3)
#define F1_BASE 42          // conv1: 2  frags (mt 0..1), K=5 pad 32, pre-scaled by log2e
#define NFRAGS 44

typedef unsigned short u16;
typedef unsigned int u32;
typedef __attribute__((ext_vector_type(8))) short bf16x8;   // 8 bf16 = 4 VGPR
typedef __attribute__((ext_vector_type(4))) float f32x4;    // MFMA acc

__device__ __forceinline__ float exp2_f(float x) {
#if __has_builtin(__builtin_amdgcn_exp2f)
    return __builtin_amdgcn_exp2f(x);
#else
    float r; asm("v_exp_f32 %0, %1" : "=v"(r) : "v"(x)); return r;
#endif
}
// scaled-domain elu: y = x*log2e in, elu(x)*log2e out.
// neg branch: (e^x - 1)*log2e = 2^y*log2e - log2e  -> one fma
__device__ __forceinline__ float eluc_f(float y) {
    float t = exp2_f(fminf(y, 0.0f));
    return fmaxf(y, fmaf(t, LOG2E, -LOG2E));
}
__device__ __forceinline__ float rcp_f(float x) {
    return __builtin_amdgcn_rcpf(x);
}
__device__ __forceinline__ float sq_f(float x) { return x * x; }
__device__ __forceinline__ u16 f2bf(float f) {              // RNE
    union { float f; u32 u; } v; v.f = f;
    u32 r = v.u + 0x7FFFu + ((v.u >> 16) & 1u);
    return (u16)(r >> 16);
}
// pack two floats to bf16x2 by truncation: single v_perm_b32
__device__ __forceinline__ u32 pack_trunc(float a, float b) {
    union { float f; u32 u; } va, vb; va.f = a; vb.f = b;
#if __has_builtin(__builtin_amdgcn_perm)
    return __builtin_amdgcn_perm(vb.u, va.u, 0x07060302u);  // [a.b2,a.b3,b.b2,b.b3]
#else
    return (vb.u & 0xFFFF0000u) | (va.u >> 16);
#endif
}
__device__ __forceinline__ u32 pack_rne(float a, float b) {
    return (u32)f2bf(a) | ((u32)f2bf(b) << 16);
}

// ---- setup kernel: build all MFMA A-operand weight frags once per launch ----
__global__ __launch_bounds__(64) void build_frags_kernel(
    const float* __restrict__ w1, const float* __restrict__ w2,
    const float* __restrict__ w3, const float* __restrict__ w4,
    const float* __restrict__ w5, u16* __restrict__ ws)
{
    const int f = blockIdx.x;      // 0..43
    const int lane = threadIdx.x;  // 0..63
    const int m = lane & 15;
    const int q = lane >> 4;
    float wvv[8];
    #pragma unroll
    for (int j = 0; j < 8; ++j) wvv[j] = 0.0f;

    if (f < F3_BASE) {                       // conv2: 20->40 k=5, K-dim = dk*32+ic
        int mt = (f - F2_BASE) / 5, s = (f - F2_BASE) % 5;
        int oc = mt * 16 + m;
        #pragma unroll
        for (int j = 0; j < 8; ++j) {
            int ic = q * 8 + j;
            if (oc < 40 && ic < 20) wvv[j] = w2[oc * 100 + ic * 5 + s];
        }
    } else if (f < F4_BASE) {                // conv3: 40->80 k=1, K=40 pad 64
        int mt = (f - F3_BASE) / 2, s = (f - F3_BASE) % 2;
        int oc = mt * 16 + m;
        #pragma unroll
        for (int j = 0; j < 8; ++j) {
            int k = s * 32 + q * 8 + j;
            if (k < 40) wvv[j] = w3[oc * 40 + k];
        }
    } else if (f < F5_BASE) {                // conv4: 80->40 k=1, K=80 pad 96
        int mt = (f - F4_BASE) / 3, s = (f - F4_BASE) % 3;
        int oc = mt * 16 + m;
        #pragma unroll
        for (int j = 0; j < 8; ++j) {
            int k = s * 32 + q * 8 + j;
            if (oc < 40 && k < 80) wvv[j] = w4[oc * 80 + k];
        }
    } else if (f < F1_BASE) {                // conv5: 40->20 k=3, K=120: k=dk*40+ic
        int mt = (f - F5_BASE) / 4, s = (f - F5_BASE) % 4;
        int oc = mt * 16 + m;
        int k0 = s * 32 + q * 8;
        int dk = k0 / 40, ic0 = k0 - dk * 40;
        #pragma unroll
        for (int j = 0; j < 8; ++j) {
            if (oc < 20 && k0 < 120) wvv[j] = w5[oc * 120 + (ic0 + j) * 3 + dk];
        }
    } else {                                 // conv1: 1->20 k=5, K=5 pad 32 (x log2e)
        int mt = f - F1_BASE;                // 0..1
        int oc = mt * 16 + m;
        #pragma unroll
        for (int j = 0; j < 8; ++j) {
            int k = q * 8 + j;
            if (oc < 20 && k < 5) wvv[j] = w1[oc * 5 + k] * LOG2E;
        }
    }
    u32 pk[4];
    #pragma unroll
    for (int p = 0; p < 4; ++p)
        pk[p] = (u32)f2bf(wvv[2 * p]) | ((u32)f2bf(wvv[2 * p + 1]) << 16);
    u32* wp = (u32*)&ws[(f * 64 + lane) * 8];
    wp[0] = pk[0]; wp[1] = pk[1]; wp[2] = pk[2]; wp[3] = pk[3];
}

__device__ __forceinline__ bf16x8 ld_frag(const u16* ws, int f, int lane) {
    return *(const bf16x8*)&ws[(f * 64 + lane) * 8];
}

__global__ __launch_bounds__(NTHREADS, 2) void weno_nn_kernel(
    const float* __restrict__ uu, const float* __restrict__ e_ptr,
    const float* __restrict__ w1, const float* __restrict__ b1,
    const float* __restrict__ b2, const float* __restrict__ b3,
    const float* __restrict__ b4, const float* __restrict__ b5,
    const float* __restrict__ w6, const float* __restrict__ b6,
    const u16* __restrict__ wfr,
    float* __restrict__ out, int n_out, int N)
{
    __shared__ float s_uu[NUU];                         // 520 B
    __shared__ u32 s_difh[NDIFP];                       // 576 B packed (dif[d],dif[d+1]); beta overlays
    __shared__ __align__(16) u16 bufA[4 * WREG];        // 21120 B: per-wave x1(34x40) -> t3(30x88)
    __shared__ __align__(16) u16 bufB[(NP + 2) * 40];   // 9760 B: x2T(120x40) -> x4T(122x40)

    float* s_beta = (float*)s_difh;

    const int tid  = threadIdx.x;
    const int lane = tid & 63;
    const int wv_id = __builtin_amdgcn_readfirstlane(tid >> 6);  // 0..3
    const int m    = lane & 15;         // M/N index within frag
    const int q    = lane >> 4;         // quad, 0..3
    const int J0   = blockIdx.x * TOUT;
    const int P0   = J0 + 2;
    const int U0   = J0 - 4;

    u16* xw = &bufA[wv_id * WREG];      // wave-private region: x1 rows then t3 rows

    // ================= stage 0: uu tile =================
    for (int i = tid; i < NUU; i += NTHREADS) {
        int g = U0 + i;
        s_uu[i] = (g >= 0 && g < N) ? uu[g] : 0.0f;
    }
    __syncthreads();

    // ================= avg-diff -> packed bf16 pairs =================
    {
        auto difval = [&](int d) -> float {
            if (d >= NDIF) return 0.0f;
            int g = P0 - 5 + d;
            if (g < 0 || g >= N) return 0.0f;
            int j1 = g < N - 2 ? g : N - 2;
            int j0 = g - 1 > 0 ? g - 1 : 0;
            float dl = s_uu[j1 + 1 - U0] - s_uu[j1 - U0];
            float dr = s_uu[j0 + 1 - U0] - s_uu[j0 - U0];
            return 0.5f * (dl + dr);
        };
        for (int d = tid; d < NDIFP; d += NTHREADS)
            s_difh[d] = pack_rne(difval(d), difval(d + 1));
    }
    __syncthreads();

    // ======== FREE-RUN REGION: conv1 -> conv2 -> conv3 -> conv4, no barriers ========
    // 30-row wave slabs; 16-row MFMA tiles overhang -> stores predicated (lr < WROWS);
    // overhang values are discarded so the cross-slab LDS reads they do are benign.

    // ---- conv1 via MFMA: 1->20, k=5 (K pad 32), eluc -> wave-private x1 (34 rows) ----
    {
        bf16x8 a1[2];
        a1[0] = ld_frag(wfr, F1_BASE + 0, lane);
        a1[1] = ld_frag(wfr, F1_BASE + 1, lane);
        f32x4 bias1[2];
        #pragma unroll
        for (int r = 0; r < 4; ++r) {
            bias1[0][r] = b1[4 * q + r] * LOG2E;
            int oc = 16 + 4 * q + r;
            bias1[1][r] = (oc < 20) ? b1[oc] * LOG2E : 0.0f;
        }
        #pragma unroll
        for (int it = 0; it < 3; ++it) {             // 3 tiles cover 48 >= 34 rows
            const int li = it * 16 + m;              // local x1 row 0..47
            const int pos = wv_id * WROWS + li;      // global x1 row (<= 137)
            bf16x8 bfrag;
            u32* bw = (u32*)&bfrag;
            bw[0] = s_difh[pos];                     // dif[pos], dif[pos+1]
            bw[1] = s_difh[pos + 2];                 // dif[pos+2], dif[pos+3]
            bw[2] = s_difh[pos + 4];                 // dif[pos+4], junk*0
            bw[3] = 0;
            f32x4 acc0 = bias1[0];
            f32x4 acc1 = bias1[1];
            acc0 = __builtin_amdgcn_mfma_f32_16x16x32_bf16(a1[0], bfrag, acc0, 0, 0, 0);
            acc1 = __builtin_amdgcn_mfma_f32_16x16x32_bf16(a1[1], bfrag, acc1, 0, 0, 0);
            if (li < WROWS + 4) {                    // rows needed by conv2
                int g = P0 - 3 + pos;
                bool valid = (g >= 0 && g < N);
                float e0 = valid ? eluc_f(acc0[0]) : 0.0f;
                float e1 = valid ? eluc_f(acc0[1]) : 0.0f;
                float e2 = valid ? eluc_f(acc0[2]) : 0.0f;
                float e3 = valid ? eluc_f(acc0[3]) : 0.0f;
                u32* wp = (u32*)&xw[li * X1S + 4 * q];
                wp[0] = pack_trunc(e0, e1);
                wp[1] = pack_trunc(e2, e3);
                if (q == 0) {                        // oc 16..19
                    float f0 = valid ? eluc_f(acc1[0]) : 0.0f;
                    float f1 = valid ? eluc_f(acc1[1]) : 0.0f;
                    float f2 = valid ? eluc_f(acc1[2]) : 0.0f;
                    float f3 = valid ? eluc_f(acc1[3]) : 0.0f;
                    u32* wp2 = (u32*)&xw[li * X1S + 16];
                    wp2[0] = pack_trunc(f0, f1);
                    wp2[1] = pack_trunc(f2, f3);
                } else {                             // zero-pad cols 20..31
                    u32* wpz = (u32*)&xw[li * X1S + 20 + (q - 1) * 4];
                    wpz[0] = 0; wpz[1] = 0;
                }
            }
        }
    }
    __builtin_amdgcn_sched_barrier(0);

    // ---- conv2: 20->40, k=5 (im2col K=160), wave-local -> x2T rows in bufB ----
    {
        bf16x8 a2[3][5];
        #pragma unroll
        for (int mt = 0; mt < 3; ++mt)
            #pragma unroll
            for (int s = 0; s < 5; ++s)
                a2[mt][s] = ld_frag(wfr, F2_BASE + mt * 5 + s, lane);
        f32x4 bias2[3];
        #pragma unroll
        for (int mt = 0; mt < 3; ++mt) {
            #pragma unroll
            for (int r = 0; r < 4; ++r) {
                int oc = mt * 16 + 4 * q + r;
                bias2[mt][r] = (oc < 40) ? b2[oc] * LOG2E : 0.0f;
            }
        }
        for (int t = 0; t < 2; ++t) {
            const int lr = t * 16 + m;               // local row (0..31)
            const int gr = wv_id * WROWS + lr;       // global row
            f32x4 acc[3];
            #pragma unroll
            for (int mt = 0; mt < 3; ++mt) acc[mt] = bias2[mt];
            #pragma unroll
            for (int s = 0; s < 5; ++s) {
                bf16x8 bfrag = *(const bf16x8*)&xw[(lr + s) * X1S + q * 8];
                #pragma unroll
                for (int mt = 0; mt < 3; ++mt)
                    acc[mt] = __builtin_amdgcn_mfma_f32_16x16x32_bf16(a2[mt][s], bfrag, acc[mt], 0, 0, 0);
            }
            #pragma unroll
            for (int mt = 0; mt < 3; ++mt) {
                int oc0 = mt * 16 + 4 * q;
                if (lr < WROWS && oc0 < 40) {
                    u32* wp = (u32*)&bufB[gr * 40 + oc0];
                    wp[0] = pack_trunc(eluc_f(acc[mt][0]), eluc_f(acc[mt][1]));
                    wp[1] = pack_trunc(eluc_f(acc[mt][2]), eluc_f(acc[mt][3]));
                }
            }
        }
    }
    __builtin_amdgcn_sched_barrier(0);

    // ---- conv3: 40->80, k=1 (K=40 pad 64), wave-local -> t3 over own x1 region ----
    {
        bf16x8 a3[5][2];
        #pragma unroll
        for (int mt = 0; mt < 5; ++mt)
            #pragma unroll
            for (int s = 0; s < 2; ++s)
                a3[mt][s] = ld_frag(wfr, F3_BASE + mt * 2 + s, lane);
        f32x4 bias3[5];
        #pragma unroll
        for (int mt = 0; mt < 5; ++mt) {
            #pragma unroll
            for (int r = 0; r < 4; ++r) bias3[mt][r] = b3[mt * 16 + 4 * q + r] * LOG2E;
        }
        for (int t = 0; t < 2; ++t) {
            const int lr = t * 16 + m;
            const int gr = wv_id * WROWS + lr;
            f32x4 acc[5];
            #pragma unroll
            for (int mt = 0; mt < 5; ++mt) acc[mt] = bias3[mt];
            // s=0: k 0..31
            {
                bf16x8 bfrag = *(const bf16x8*)&bufB[gr * 40 + q * 8];
                #pragma unroll
                for (int mt = 0; mt < 5; ++mt)
                    acc[mt] = __builtin_amdgcn_mfma_f32_16x16x32_bf16(a3[mt][0], bfrag, acc[mt], 0, 0, 0);
            }
            // s=1: only q==0 has valid k (32..39); other quads multiply zero A-weights
            {
                bf16x8 bfrag = *(const bf16x8*)&bufB[gr * 40 + ((q == 0) ? 32 : 0)];
                #pragma unroll
                for (int mt = 0; mt < 5; ++mt)
                    acc[mt] = __builtin_amdgcn_mfma_f32_16x16x32_bf16(a3[mt][1], bfrag, acc[mt], 0, 0, 0);
            }
            #pragma unroll
            for (int mt = 0; mt < 5; ++mt) {
                int oc0 = mt * 16 + 4 * q;           // 0..76
                if (lr < WROWS) {
                    u32* wp = (u32*)&xw[lr * T3S + oc0];
                    wp[0] = pack_trunc(eluc_f(acc[mt][0]), eluc_f(acc[mt][1]));
                    wp[1] = pack_trunc(eluc_f(acc[mt][2]), eluc_f(acc[mt][3]));
                }
            }
        }
    }
    __builtin_amdgcn_sched_barrier(0);

    // ---- conv4: 80->40, k=1 (K=80 pad 96), wave-local -> x4T rows in bufB ----
    {
        bf16x8 a4[3][3];
        #pragma unroll
        for (int mt = 0; mt < 3; ++mt)
            #pragma unroll
            for (int s = 0; s < 3; ++s)
                a4[mt][s] = ld_frag(wfr, F4_BASE + mt * 3 + s, lane);
        f32x4 bias4[3];
        #pragma unroll
        for (int mt = 0; mt < 3; ++mt) {
            #pragma unroll
            for (int r = 0; r < 4; ++r) {
                int oc = mt * 16 + 4 * q + r;
                bias4[mt][r] = (oc < 40) ? b4[oc] * LOG2E : 0.0f;
            }
        }
        // zero-pad x4T rows NP, NP+1 (conv5 right-edge halo; never hold x2)
        if (tid < 80) bufB[NP * 40 + tid] = 0;
        for (int t = 0; t < 2; ++t) {
            const int lr = t * 16 + m;
            const int gr = wv_id * WROWS + lr;
            f32x4 acc[3];
            #pragma unroll
            for (int mt = 0; mt < 3; ++mt) acc[mt] = bias4[mt];
            #pragma unroll
            for (int s = 0; s < 3; ++s) {
                int k0 = s * 32 + q * 8;
                // k0 >= 80 lanes have zero A-weights; clamp address
                bf16x8 bfrag = *(const bf16x8*)&xw[lr * T3S + ((k0 < 80) ? k0 : 0)];
                #pragma unroll
                for (int mt = 0; mt < 3; ++mt)
                    acc[mt] = __builtin_amdgcn_mfma_f32_16x16x32_bf16(a4[mt][s], bfrag, acc[mt], 0, 0, 0);
            }
            #pragma unroll
            for (int mt = 0; mt < 3; ++mt) {
                int oc0 = mt * 16 + 4 * q;
                if (lr < WROWS && oc0 < 40) {
                    u32* wp = (u32*)&bufB[gr * 40 + oc0];
                    wp[0] = pack_trunc(eluc_f(acc[mt][0]), eluc_f(acc[mt][1]));
                    wp[1] = pack_trunc(eluc_f(acc[mt][2]), eluc_f(acc[mt][3]));
                }
            }
        }
    }
    __syncthreads();   // conv5 reads x4 cross-wave

    // ===== conv5 (40->20, k=3, K=120) + fused conv6 (20->1) -> beta =====
    {
        bf16x8 a5[2][4];
        #pragma unroll
        for (int mt = 0; mt < 2; ++mt)
            #pragma unroll
            for (int s = 0; s < 4; ++s)
                a5[mt][s] = ld_frag(wfr, F5_BASE + mt * 4 + s, lane);
        f32x4 bias5[2];
        #pragma unroll
        for (int mt = 0; mt < 2; ++mt) {
            #pragma unroll
            for (int r = 0; r < 4; ++r) {
                int oc = mt * 16 + 4 * q + r;
                bias5[mt][r] = (oc < 20) ? b5[oc] * LOG2E : 0.0f;
            }
        }
        float w6a[4], w6b[4];
        #pragma unroll
        for (int r = 0; r < 4; ++r) {
            w6a[r] = w6[4 * q + r] * LN2;            // unscale conv5's scaled activations
            w6b[r] = (q == 0) ? w6[16 + r] * LN2 : 0.0f;
        }
        const float b6v = b6[0];

        for (int t = 0; t < 2; ++t) {
            const int N0 = (wv_id * 2 + t) * 16;
            const int row = N0 + m;
            f32x4 acc[2];
            #pragma unroll
            for (int mt = 0; mt < 2; ++mt) acc[mt] = bias5[mt];
            #pragma unroll
            for (int s = 0; s < 4; ++s) {
                int k0 = s * 32 + q * 8;
                int dk = (k0 < 120) ? (k0 / 40) : 0;
                int ic0 = (k0 < 120) ? (k0 - dk * 40) : 0;
                int rr = row + dk;
                rr = (rr < NP + 2) ? rr : (NP + 1);  // clamp (in-bounds; tail rows discarded)
                bf16x8 bfrag = *(const bf16x8*)&bufB[rr * 40 + ic0];
                #pragma unroll
                for (int mt = 0; mt < 2; ++mt)
                    acc[mt] = __builtin_amdgcn_mfma_f32_16x16x32_bf16(a5[mt][s], bfrag, acc[mt], 0, 0, 0);
            }
            float p = 0.0f;
            #pragma unroll
            for (int r = 0; r < 4; ++r) p += w6a[r] * eluc_f(acc[0][r]);
            #pragma unroll
            for (int r = 0; r < 4; ++r) p += w6b[r] * eluc_f(acc[1][r]);
            p += __shfl_xor(p, 16);
            p += __shfl_xor(p, 32);
            float aa = p + b6v;
            if (q == 0 && row < NP)
                s_beta[row] = rcp_f(1.0f + __expf(-aa)) + 0.1f;
        }
    }
    __syncthreads();

    // ================= WENO5 =================
    const float eps = e_ptr[0];
    if (tid < TOUT) {
        int j = J0 + tid;
        if (j < n_out) {
            float a  = s_uu[tid + 5];
            float b  = s_uu[tid + 6];
            float c  = s_uu[tid + 7];
            float d  = s_uu[tid + 8];
            float ee = s_uu[tid + 9];
            float f  = s_uu[tid + 10];
            float m0 = s_beta[tid];
            float m1 = s_beta[tid + 1];
            float m2 = s_beta[tid + 2];

            const float i6 = 1.0f / 6.0f;
            float fp0 = (11.f * d - 7.f * ee + 2.f * f) * i6;
            float fp1 = (2.f * c + 5.f * d - ee) * i6;
            float fp2 = (-b + 5.f * c + 2.f * d) * i6;
            float fn0 = (11.f * c - 7.f * d + 2.f * ee) * i6;
            float fn1 = (2.f * b + 5.f * c - d) * i6;
            float fn2 = (-a + 5.f * b + 2.f * c) * i6;

            const float c1312 = 13.f / 12.f;
            float bp0 = c1312 * sq_f(d - 2.f * ee + f) + 0.25f * sq_f(3.f * d - 4.f * ee + f);
            float bp1 = c1312 * sq_f(c - 2.f * d + ee) + 0.25f * sq_f(c - ee);
            float bp2 = c1312 * sq_f(b - 2.f * c + d) + 0.25f * sq_f(b - 4.f * c + 3.f * d);
            float bn0 = c1312 * sq_f(c - 2.f * d + ee) + 0.25f * sq_f(3.f * c - 4.f * d + ee);
            float bn1 = c1312 * sq_f(b - 2.f * c + d) + 0.25f * sq_f(b - d);
            float bn2 = c1312 * sq_f(a - 2.f * b + c) + 0.25f * sq_f(a - 4.f * b + 3.f * c);

            bp0 *= m0; bp1 *= m1; bp2 *= m2;
            bn0 *= m0; bn1 *= m1; bn2 *= m2;

            float q0 = eps + bp0; q0 *= q0;
            float q1 = eps + bp1; q1 *= q1;
            float q2 = eps + bp2; q2 *= q2;
            float brs = bp2 - bp0; brs *= brs;
            float o0 = 0.1f * (1.f + brs * rcp_f(q0));
            float o1 = 0.6f * (1.f + brs * rcp_f(q1));
            float o2 = 0.3f * (1.f + brs * rcp_f(q2));
            float inv = rcp_f(o0 + o1 + o2);
            float fluxp = (o0 * fp0 + o1 * fp1 + o2 * fp2) * inv;

            q0 = eps + bn0; q0 *= q0;
            q1 = eps + bn1; q1 *= q1;
            q2 = eps + bn2; q2 *= q2;
            brs = bn2 - bn0; brs *= brs;
            o0 = 0.1f * (1.f + brs * rcp_f(q0));
            o1 = 0.6f * (1.f + brs * rcp_f(q1));
            o2 = 0.3f * (1.f + brs * rcp_f(q2));
            inv = rcp_f(o0 + o1 + o2);
            float fluxn = (o0 * fn0 + o1 * fn1 + o2 * fn2) * inv;

            out[j] = fluxp - fluxn;
        }
    }
}

extern "C" void kernel_launch(void* const* d_in, const int* in_sizes, int n_in,
                              void* d_out, int out_size, void* d_ws, size_t ws_size,
                              hipStream_t stream) {
    const float* uu = (const float*)d_in[0];
    const float* e  = (const float*)d_in[1];
    const float* w1 = (const float*)d_in[2];
    const float* b1 = (const float*)d_in[3];
    const float* w2 = (const float*)d_in[4];
    const float* b2 = (const float*)d_in[5];
    const float* w3 = (const float*)d_in[6];
    const float* b3 = (const float*)d_in[7];
    const float* w4 = (const float*)d_in[8];
    const float* b4 = (const float*)d_in[9];
    const float* w5 = (const float*)d_in[10];
    const float* b5 = (const float*)d_in[11];
    const float* w6 = (const float*)d_in[12];
    const float* b6 = (const float*)d_in[13];
    float* out = (float*)d_out;
    u16* wfr = (u16*)d_ws;
    const int N = in_sizes[0];
    const int nblocks = (out_size + TOUT - 1) / TOUT;

    build_frags_kernel<<<NFRAGS, 64, 0, stream>>>(w1, w2, w3, w4, w5, wfr);
    weno_nn_kernel<<<nblocks, NTHREADS, 0, stream>>>(
        uu, e, w1, b1, b2, b3, b4, b5, w6, b6, wfr,
        out, out_size, N);
}

// Round 8
// 279.958 us; speedup vs baseline: 1.0553x; 1.0553x over previous
//
#include <hip/hip_runtime.h>
#include <math.h>

#define NTHREADS 256
#define TOUT 126            // outputs per block
#define NP 128              // conv2/3/4/5 positions, base P0-1
#define X1S 40              // x1 row stride (u16), cols 20..31 zeroed
#define T3S 88              // t3 row stride (u16): 176B = 11x16B (odd) -> 2-way banks
#define NDIF 136            // real dif entries, base P0-5
#define NDIFP 148           // padded difh array (conv1-MFMA reads up to 147)
#define NUU 138             // uu, base J0-4
#define WREG 2816           // u16 per wave-private region (x1 36x40 -> t3 32x88)
#define LOG2E 1.44269504f

// weight-fragment table in d_ws: 44 frags x 64 lanes x 8 bf16 (16 B)
#define F2_BASE 0           // conv2: 15 frags (mt 0..2, s 0..4)
#define F3_BASE 15          // conv3: 10 frags (mt 0..4, s 0..1)
#define F4_BASE 25          // conv4: 9  frags (mt 0..2, s 0..2)
#define F5_BASE 34          // conv5: 8  frags (mt 0..1, s 0..3)
#define F1_BASE 42          // conv1: 2  frags (mt 0..1), K=5 pad 32, pre-scaled by log2e
#define NFRAGS 44

typedef unsigned short u16;
typedef unsigned int u32;
typedef __attribute__((ext_vector_type(8))) short bf16x8;   // 8 bf16 = 4 VGPR
typedef __attribute__((ext_vector_type(4))) float f32x4;    // MFMA acc

__device__ __forceinline__ float exp2_f(float x) {
#if __has_builtin(__builtin_amdgcn_exp2f)
    return __builtin_amdgcn_exp2f(x);
#else
    float r; asm("v_exp_f32 %0, %1" : "=v"(r) : "v"(x)); return r;
#endif
}
// scaled-domain elu: y = x*log2e in, elu(x)*log2e out.
// neg branch: (e^x - 1)*log2e = 2^y*log2e - log2e -> one fma
__device__ __forceinline__ float eluc_f(float y) {
    float t = exp2_f(fminf(y, 0.0f));
    return fmaxf(y, fmaf(t, LOG2E, -LOG2E));
}
__device__ __forceinline__ float rcp_f(float x) {
    return __builtin_amdgcn_rcpf(x);
}
__device__ __forceinline__ float sq_f(float x) { return x * x; }
__device__ __forceinline__ u16 f2bf(float f) {              // RNE
    union { float f; u32 u; } v; v.f = f;
    u32 r = v.u + 0x7FFFu + ((v.u >> 16) & 1u);
    return (u16)(r >> 16);
}
// pack two floats to bf16x2 by truncation: single v_perm_b32
__device__ __forceinline__ u32 pack_trunc(float a, float b) {
    union { float f; u32 u; } va, vb; va.f = a; vb.f = b;
#if __has_builtin(__builtin_amdgcn_perm)
    return __builtin_amdgcn_perm(vb.u, va.u, 0x07060302u);  // [a.b2,a.b3,b.b2,b.b3]
#else
    return (vb.u & 0xFFFF0000u) | (va.u >> 16);
#endif
}
__device__ __forceinline__ u32 pack_rne(float a, float b) {
    return (u32)f2bf(a) | ((u32)f2bf(b) << 16);
}

// ---- setup kernel: build all MFMA A-operand weight frags once per launch ----
__global__ __launch_bounds__(64) void build_frags_kernel(
    const float* __restrict__ w1, const float* __restrict__ w2,
    const float* __restrict__ w3, const float* __restrict__ w4,
    const float* __restrict__ w5, u16* __restrict__ ws)
{
    const int f = blockIdx.x;      // 0..43
    const int lane = threadIdx.x;  // 0..63
    const int m = lane & 15;
    const int q = lane >> 4;
    float wvv[8];
    #pragma unroll
    for (int j = 0; j < 8; ++j) wvv[j] = 0.0f;

    if (f < F3_BASE) {                       // conv2: 20->40 k=5, K-dim = dk*32+ic
        int mt = (f - F2_BASE) / 5, s = (f - F2_BASE) % 5;
        int oc = mt * 16 + m;
        #pragma unroll
        for (int j = 0; j < 8; ++j) {
            int ic = q * 8 + j;
            if (oc < 40 && ic < 20) wvv[j] = w2[oc * 100 + ic * 5 + s];
        }
    } else if (f < F4_BASE) {                // conv3: 40->80 k=1, K=40 pad 64
        int mt = (f - F3_BASE) / 2, s = (f - F3_BASE) % 2;
        int oc = mt * 16 + m;
        #pragma unroll
        for (int j = 0; j < 8; ++j) {
            int k = s * 32 + q * 8 + j;
            if (k < 40) wvv[j] = w3[oc * 40 + k];
        }
    } else if (f < F5_BASE) {                // conv4: 80->40 k=1, K=80 pad 96
        int mt = (f - F4_BASE) / 3, s = (f - F4_BASE) % 3;
        int oc = mt * 16 + m;
        #pragma unroll
        for (int j = 0; j < 8; ++j) {
            int k = s * 32 + q * 8 + j;
            if (oc < 40 && k < 80) wvv[j] = w4[oc * 80 + k];
        }
    } else if (f < F1_BASE) {                // conv5: 40->20 k=3, K=120: k=dk*40+ic
        int mt = (f - F5_BASE) / 4, s = (f - F5_BASE) % 4;
        int oc = mt * 16 + m;
        int k0 = s * 32 + q * 8;
        int dk = k0 / 40, ic0 = k0 - dk * 40;
        #pragma unroll
        for (int j = 0; j < 8; ++j) {
            if (oc < 20 && k0 < 120) wvv[j] = w5[oc * 120 + (ic0 + j) * 3 + dk];
        }
    } else {                                 // conv1: 1->20 k=5, K=5 pad 32 (x log2e)
        int mt = f - F1_BASE;                // 0..1
        int oc = mt * 16 + m;
        #pragma unroll
        for (int j = 0; j < 8; ++j) {
            int k = q * 8 + j;
            if (oc < 20 && k < 5) wvv[j] = w1[oc * 5 + k] * LOG2E;
        }
    }
    u32 pk[4];
    #pragma unroll
    for (int p = 0; p < 4; ++p)
        pk[p] = (u32)f2bf(wvv[2 * p]) | ((u32)f2bf(wvv[2 * p + 1]) << 16);
    u32* wp = (u32*)&ws[(f * 64 + lane) * 8];
    wp[0] = pk[0]; wp[1] = pk[1]; wp[2] = pk[2]; wp[3] = pk[3];
}

__device__ __forceinline__ bf16x8 ld_frag(const u16* ws, int f, int lane) {
    return *(const bf16x8*)&ws[(f * 64 + lane) * 8];
}

__global__ __launch_bounds__(NTHREADS, 2) void weno_nn_kernel(
    const float* __restrict__ uu, const float* __restrict__ e_ptr,
    const float* __restrict__ w1, const float* __restrict__ b1,
    const float* __restrict__ b2, const float* __restrict__ b3,
    const float* __restrict__ b4, const float* __restrict__ b5,
    const float* __restrict__ w6, const float* __restrict__ b6,
    const u16* __restrict__ wfr,
    float* __restrict__ out, int n_out, int N)
{
    __shared__ float s_uu[NUU];                         // 552 B
    __shared__ u32 s_difh[NDIFP];                       // 592 B packed (dif[d],dif[d+1]); beta overlays
    __shared__ __align__(16) u16 bufA[4 * WREG];        // 22528 B: per-wave x1(36x40) -> t3(32x88)
    __shared__ __align__(16) u16 bufB[130 * 40];        // 10400 B: x2T(128x40) -> x4T(130x40)

    float* s_beta = (float*)s_difh;

    const int tid  = threadIdx.x;
    const int lane = tid & 63;
    const int wv_id = __builtin_amdgcn_readfirstlane(tid >> 6);  // 0..3
    const int m    = lane & 15;         // M/N index within frag
    const int q    = lane >> 4;         // quad, 0..3
    const int J0   = blockIdx.x * TOUT;
    const int P0   = J0 + 2;
    const int U0   = J0 - 4;

    u16* xw = &bufA[wv_id * WREG];      // wave-private region: x1 rows then t3 rows

    // ================= stage 0: uu tile =================
    for (int i = tid; i < NUU; i += NTHREADS) {
        int g = U0 + i;
        s_uu[i] = (g >= 0 && g < N) ? uu[g] : 0.0f;
    }
    __syncthreads();

    // ================= avg-diff -> packed bf16 pairs (dif[d], dif[d+1]) =================
    {
        auto difval = [&](int d) -> float {
            if (d >= NDIF) return 0.0f;
            int g = P0 - 5 + d;
            if (g < 0 || g >= N) return 0.0f;
            int j1 = g < N - 2 ? g : N - 2;
            int j0 = g - 1 > 0 ? g - 1 : 0;
            float dl = s_uu[j1 + 1 - U0] - s_uu[j1 - U0];
            float dr = s_uu[j0 + 1 - U0] - s_uu[j0 - U0];
            return 0.5f * (dl + dr);
        };
        for (int d = tid; d < NDIFP; d += NTHREADS)
            s_difh[d] = pack_rne(difval(d), difval(d + 1));
    }
    __syncthreads();

    // ======== FREE-RUN REGION: conv1 -> conv2 -> conv3 -> conv4, no barriers ========
    // Each wave computes its own x1 halo (36 rows) and keeps conv2/3/4 wave-local.
    // sched_barrier(0) pins per-phase codegen (prevents frag-load hoisting / VGPR blow-up).

    // ---- conv1 via MFMA: 1->20, k=5 (K pad 32), eluc -> wave-private x1 (36 rows) ----
    {
        bf16x8 a1[2];
        a1[0] = ld_frag(wfr, F1_BASE + 0, lane);
        a1[1] = ld_frag(wfr, F1_BASE + 1, lane);
        f32x4 bias1[2];
        #pragma unroll
        for (int r = 0; r < 4; ++r) {
            bias1[0][r] = b1[4 * q + r] * LOG2E;
            int oc = 16 + 4 * q + r;
            bias1[1][r] = (oc < 20) ? b1[oc] * LOG2E : 0.0f;
        }
        #pragma unroll
        for (int it = 0; it < 3; ++it) {             // 3 tiles cover 48 >= 36 rows
            const int li = it * 16 + m;              // local x1 row 0..47
            const int pos = wv_id * 32 + li;         // global x1 row (<= 143)
            bf16x8 bfrag;
            u32* bw = (u32*)&bfrag;
            bw[0] = s_difh[pos];                     // dif[pos], dif[pos+1]
            bw[1] = s_difh[pos + 2];                 // dif[pos+2], dif[pos+3]
            bw[2] = s_difh[pos + 4];                 // dif[pos+4], junk*0
            bw[3] = 0;
            f32x4 acc0 = bias1[0];
            f32x4 acc1 = bias1[1];
            acc0 = __builtin_amdgcn_mfma_f32_16x16x32_bf16(a1[0], bfrag, acc0, 0, 0, 0);
            acc1 = __builtin_amdgcn_mfma_f32_16x16x32_bf16(a1[1], bfrag, acc1, 0, 0, 0);
            if (li < 36) {                           // rows needed: conv2 reads li 0..35
                int g = P0 - 3 + pos;
                bool valid = (g >= 0 && g < N);
                float e0 = valid ? eluc_f(acc0[0]) : 0.0f;
                float e1 = valid ? eluc_f(acc0[1]) : 0.0f;
                float e2 = valid ? eluc_f(acc0[2]) : 0.0f;
                float e3 = valid ? eluc_f(acc0[3]) : 0.0f;
                u32* wp = (u32*)&xw[li * X1S + 4 * q];
                wp[0] = pack_trunc(e0, e1);
                wp[1] = pack_trunc(e2, e3);
                if (q == 0) {                        // oc 16..19
                    float f0 = valid ? eluc_f(acc1[0]) : 0.0f;
                    float f1 = valid ? eluc_f(acc1[1]) : 0.0f;
                    float f2 = valid ? eluc_f(acc1[2]) : 0.0f;
                    float f3 = valid ? eluc_f(acc1[3]) : 0.0f;
                    u32* wp2 = (u32*)&xw[li * X1S + 16];
                    wp2[0] = pack_trunc(f0, f1);
                    wp2[1] = pack_trunc(f2, f3);
                } else {                             // zero-pad cols 20..31
                    u32* wpz = (u32*)&xw[li * X1S + 20 + (q - 1) * 4];
                    wpz[0] = 0; wpz[1] = 0;
                }
            }
        }
    }
    __builtin_amdgcn_sched_barrier(0);

    // ---- conv2: 20->40, k=5 (im2col K=160), wave-local -> x2T rows in bufB ----
    {
        bf16x8 a2[3][5];
        #pragma unroll
        for (int mt = 0; mt < 3; ++mt)
            #pragma unroll
            for (int s = 0; s < 5; ++s)
                a2[mt][s] = ld_frag(wfr, F2_BASE + mt * 5 + s, lane);
        f32x4 bias2[3];
        #pragma unroll
        for (int mt = 0; mt < 3; ++mt) {
            #pragma unroll
            for (int r = 0; r < 4; ++r) {
                int oc = mt * 16 + 4 * q + r;
                bias2[mt][r] = (oc < 40) ? b2[oc] * LOG2E : 0.0f;
            }
        }
        for (int t = 0; t < 2; ++t) {
            const int lr = t * 16 + m;               // local row
            const int gr = wv_id * 32 + lr;          // global row
            f32x4 acc[3];
            #pragma unroll
            for (int mt = 0; mt < 3; ++mt) acc[mt] = bias2[mt];
            #pragma unroll
            for (int s = 0; s < 5; ++s) {
                bf16x8 bfrag = *(const bf16x8*)&xw[(lr + s) * X1S + q * 8];
                #pragma unroll
                for (int mt = 0; mt < 3; ++mt)
                    acc[mt] = __builtin_amdgcn_mfma_f32_16x16x32_bf16(a2[mt][s], bfrag, acc[mt], 0, 0, 0);
            }
            #pragma unroll
            for (int mt = 0; mt < 3; ++mt) {
                int oc0 = mt * 16 + 4 * q;
                if (oc0 < 40) {
                    u32* wp = (u32*)&bufB[gr * 40 + oc0];
                    wp[0] = pack_trunc(eluc_f(acc[mt][0]), eluc_f(acc[mt][1]));
                    wp[1] = pack_trunc(eluc_f(acc[mt][2]), eluc_f(acc[mt][3]));
                }
            }
        }
    }
    __builtin_amdgcn_sched_barrier(0);

    // ---- conv3: 40->80, k=1 (K=40 pad 64), wave-local -> t3 over own x1 region ----
    {
        bf16x8 a3[5][2];
        #pragma unroll
        for (int mt = 0; mt < 5; ++mt)
            #pragma unroll
            for (int s = 0; s < 2; ++s)
                a3[mt][s] = ld_frag(wfr, F3_BASE + mt * 2 + s, lane);
        f32x4 bias3[5];
        #pragma unroll
        for (int mt = 0; mt < 5; ++mt) {
            #pragma unroll
            for (int r = 0; r < 4; ++r) bias3[mt][r] = b3[mt * 16 + 4 * q + r] * LOG2E;
        }
        for (int t = 0; t < 2; ++t) {
            const int lr = t * 16 + m;
            const int gr = wv_id * 32 + lr;
            f32x4 acc[5];
            #pragma unroll
            for (int mt = 0; mt < 5; ++mt) acc[mt] = bias3[mt];
            // s=0: k 0..31
            {
                bf16x8 bfrag = *(const bf16x8*)&bufB[gr * 40 + q * 8];
                #pragma unroll
                for (int mt = 0; mt < 5; ++mt)
                    acc[mt] = __builtin_amdgcn_mfma_f32_16x16x32_bf16(a3[mt][0], bfrag, acc[mt], 0, 0, 0);
            }
            // s=1: only q==0 has valid k (32..39); other quads multiply zero A-weights
            {
                bf16x8 bfrag = *(const bf16x8*)&bufB[gr * 40 + ((q == 0) ? 32 : 0)];
                #pragma unroll
                for (int mt = 0; mt < 5; ++mt)
                    acc[mt] = __builtin_amdgcn_mfma_f32_16x16x32_bf16(a3[mt][1], bfrag, acc[mt], 0, 0, 0);
            }
            #pragma unroll
            for (int mt = 0; mt < 5; ++mt) {
                int oc0 = mt * 16 + 4 * q;           // 0..76
                u32* wp = (u32*)&xw[lr * T3S + oc0];
                wp[0] = pack_trunc(eluc_f(acc[mt][0]), eluc_f(acc[mt][1]));
                wp[1] = pack_trunc(eluc_f(acc[mt][2]), eluc_f(acc[mt][3]));
            }
        }
    }
    __builtin_amdgcn_sched_barrier(0);

    // ---- conv4: 80->40, k=1 (K=80 pad 96), wave-local -> x4T rows in bufB ----
    {
        bf16x8 a4[3][3];
        #pragma unroll
        for (int mt = 0; mt < 3; ++mt)
            #pragma unroll
            for (int s = 0; s < 3; ++s)
                a4[mt][s] = ld_frag(wfr, F4_BASE + mt * 3 + s, lane);
        f32x4 bias4[3];
        #pragma unroll
        for (int mt = 0; mt < 3; ++mt) {
            #pragma unroll
            for (int r = 0; r < 4; ++r) {
                int oc = mt * 16 + 4 * q + r;
                bias4[mt][r] = (oc < 40) ? b4[oc] * LOG2E : 0.0f;
            }
        }
        // zero-pad x4T rows 128,129 (conv5 right-edge halo; rows never hold x2)
        if (tid < 80) bufB[128 * 40 + tid] = 0;
        for (int t = 0; t < 2; ++t) {
            const int lr = t * 16 + m;
            const int gr = wv_id * 32 + lr;
            f32x4 acc[3];
            #pragma unroll
            for (int mt = 0; mt < 3; ++mt) acc[mt] = bias4[mt];
            #pragma unroll
            for (int s = 0; s < 3; ++s) {
                int k0 = s * 32 + q * 8;
                // k0 >= 80 lanes have zero A-weights; clamp address
                bf16x8 bfrag = *(const bf16x8*)&xw[lr * T3S + ((k0 < 80) ? k0 : 0)];
                #pragma unroll
                for (int mt = 0; mt < 3; ++mt)
                    acc[mt] = __builtin_amdgcn_mfma_f32_16x16x32_bf16(a4[mt][s], bfrag, acc[mt], 0, 0, 0);
            }
            #pragma unroll
            for (int mt = 0; mt < 3; ++mt) {
                int oc0 = mt * 16 + 4 * q;
                if (oc0 < 40) {
                    u32* wp = (u32*)&bufB[gr * 40 + oc0];
                    wp[0] = pack_trunc(eluc_f(acc[mt][0]), eluc_f(acc[mt][1]));
                    wp[1] = pack_trunc(eluc_f(acc[mt][2]), eluc_f(acc[mt][3]));
                }
            }
        }
    }
    __syncthreads();   // conv5 reads x4 cross-wave

    // ===== conv5 (40->20, k=3, K=120) + fused conv6 (20->1) -> beta =====
    {
        bf16x8 a5[2][4];
        #pragma unroll
        for (int mt = 0; mt < 2; ++mt)
            #pragma unroll
            for (int s = 0; s < 4; ++s)
                a5[mt][s] = ld_frag(wfr, F5_BASE + mt * 4 + s, lane);
        f32x4 bias5[2];
        #pragma unroll
        for (int mt = 0; mt < 2; ++mt) {
            #pragma unroll
            for (int r = 0; r < 4; ++r) {
                int oc = mt * 16 + 4 * q + r;
                bias5[mt][r] = (oc < 20) ? b5[oc] * LOG2E : 0.0f;
            }
        }
        // conv5 activations carry x*log2e; dot with RAW w6 gives (x.w6)*log2e,
        // exactly the exp2-domain argument for the sigmoid: 1/(1+2^-aa).
        float w6a[4], w6b[4];
        #pragma unroll
        for (int r = 0; r < 4; ++r) {
            w6a[r] = w6[4 * q + r];
            w6b[r] = (q == 0) ? w6[16 + r] : 0.0f;
        }
        const float b6v = b6[0] * LOG2E;

        for (int t = 0; t < 2; ++t) {
            const int N0 = (wv_id * 2 + t) * 16;
            const int row = N0 + m;
            f32x4 acc[2];
            #pragma unroll
            for (int mt = 0; mt < 2; ++mt) acc[mt] = bias5[mt];
            #pragma unroll
            for (int s = 0; s < 4; ++s) {
                int k0 = s * 32 + q * 8;
                int dk = (k0 < 120) ? (k0 / 40) : 0;
                int ic0 = (k0 < 120) ? (k0 - dk * 40) : 0;
                bf16x8 bfrag = *(const bf16x8*)&bufB[(row + dk) * 40 + ic0];
                #pragma unroll
                for (int mt = 0; mt < 2; ++mt)
                    acc[mt] = __builtin_amdgcn_mfma_f32_16x16x32_bf16(a5[mt][s], bfrag, acc[mt], 0, 0, 0);
            }
            float p = 0.0f;
            #pragma unroll
            for (int r = 0; r < 4; ++r) p += w6a[r] * eluc_f(acc[0][r]);
            #pragma unroll
            for (int r = 0; r < 4; ++r) p += w6b[r] * eluc_f(acc[1][r]);
            p += __shfl_xor(p, 16);
            p += __shfl_xor(p, 32);
            float aa = p + b6v;
            if (q == 0)
                s_beta[row] = rcp_f(1.0f + exp2_f(-aa)) + 0.1f;
        }
    }
    __syncthreads();

    // ================= WENO5 =================
    const float eps = e_ptr[0];
    if (tid < TOUT) {
        int j = J0 + tid;
        if (j < n_out) {
            float a  = s_uu[tid + 5];
            float b  = s_uu[tid + 6];
            float c  = s_uu[tid + 7];
            float d  = s_uu[tid + 8];
            float ee = s_uu[tid + 9];
            float f  = s_uu[tid + 10];
            float m0 = s_beta[tid];
            float m1 = s_beta[tid + 1];
            float m2 = s_beta[tid + 2];

            const float i6 = 1.0f / 6.0f;
            float fp0 = (11.f * d - 7.f * ee + 2.f * f) * i6;
            float fp1 = (2.f * c + 5.f * d - ee) * i6;
            float fp2 = (-b + 5.f * c + 2.f * d) * i6;
            float fn0 = (11.f * c - 7.f * d + 2.f * ee) * i6;
            float fn1 = (2.f * b + 5.f * c - d) * i6;
            float fn2 = (-a + 5.f * b + 2.f * c) * i6;

            const float c1312 = 13.f / 12.f;
            float bp0 = c1312 * sq_f(d - 2.f * ee + f) + 0.25f * sq_f(3.f * d - 4.f * ee + f);
            float bp1 = c1312 * sq_f(c - 2.f * d + ee) + 0.25f * sq_f(c - ee);
            float bp2 = c1312 * sq_f(b - 2.f * c + d) + 0.25f * sq_f(b - 4.f * c + 3.f * d);
            float bn0 = c1312 * sq_f(c - 2.f * d + ee) + 0.25f * sq_f(3.f * c - 4.f * d + ee);
            float bn1 = c1312 * sq_f(b - 2.f * c + d) + 0.25f * sq_f(b - d);
            float bn2 = c1312 * sq_f(a - 2.f * b + c) + 0.25f * sq_f(a - 4.f * b + 3.f * c);

            bp0 *= m0; bp1 *= m1; bp2 *= m2;
            bn0 *= m0; bn1 *= m1; bn2 *= m2;

            float q0 = eps + bp0; q0 *= q0;
            float q1 = eps + bp1; q1 *= q1;
            float q2 = eps + bp2; q2 *= q2;
            float brs = bp2 - bp0; brs *= brs;
            float o0 = 0.1f * (1.f + brs * rcp_f(q0));
            float o1 = 0.6f * (1.f + brs * rcp_f(q1));
            float o2 = 0.3f * (1.f + brs * rcp_f(q2));
            float inv = rcp_f(o0 + o1 + o2);
            float fluxp = (o0 * fp0 + o1 * fp1 + o2 * fp2) * inv;

            q0 = eps + bn0; q0 *= q0;
            q1 = eps + bn1; q1 *= q1;
            q2 = eps + bn2; q2 *= q2;
            brs = bn2 - bn0; brs *= brs;
            o0 = 0.1f * (1.f + brs * rcp_f(q0));
            o1 = 0.6f * (1.f + brs * rcp_f(q1));
            o2 = 0.3f * (1.f + brs * rcp_f(q2));
            inv = rcp_f(o0 + o1 + o2);
            float fluxn = (o0 * fn0 + o1 * fn1 + o2 * fn2) * inv;

            out[j] = fluxp - fluxn;
        }
    }
}

extern "C" void kernel_launch(void* const* d_in, const int* in_sizes, int n_in,
                              void* d_out, int out_size, void* d_ws, size_t ws_size,
                              hipStream_t stream) {
    const float* uu = (const float*)d_in[0];
    const float* e  = (const float*)d_in[1];
    const float* w1 = (const float*)d_in[2];
    const float* b1 = (const float*)d_in[3];
    const float* w2 = (const float*)d_in[4];
    const float* b2 = (const float*)d_in[5];
    const float* w3 = (const float*)d_in[6];
    const float* b3 = (const float*)d_in[7];
    const float* w4 = (const float*)d_in[8];
    const float* b4 = (const float*)d_in[9];
    const float* w5 = (const float*)d_in[10];
    const float* b5 = (const float*)d_in[11];
    const float* w6 = (const float*)d_in[12];
    const float* b6 = (const float*)d_in[13];
    float* out = (float*)d_out;
    u16* wfr = (u16*)d_ws;
    const int N = in_sizes[0];
    const int nblocks = (out_size + TOUT - 1) / TOUT;

    build_frags_kernel<<<NFRAGS, 64, 0, stream>>>(w1, w2, w3, w4, w5, wfr);
    weno_nn_kernel<<<nblocks, NTHREADS, 0, stream>>>(
        uu, e, w1, b1, b2, b3, b4, b5, w6, b6, wfr,
        out, out_size, N);
}

// Round 9
// 274.670 us; speedup vs baseline: 1.0757x; 1.0193x over previous
//
#include <hip/hip_runtime.h>
#include <math.h>

#define NTHREADS 256
#define TOUT 126            // outputs per block
#define NP 128              // conv2/3/4/5 positions, base P0-1
#define X1S 40              // x1 row stride (u16), cols 20..31 zeroed
#define T3S 88              // t3 row stride (u16): 176B = 11x16B (odd) -> 2-way banks
#define X5S 26              // x5T stride: odd bank stride, conv6 conflict-free
#define NDIF 136            // real dif entries, base P0-5
#define NDIFP 148           // padded difh array (conv1-MFMA reads up to 147)
#define NUU 138             // uu, base J0-4
#define WREG 2816           // u16 per wave-private region (x1 36x40 -> t3 32x88)
#define LOG2E 1.44269504f

// weight-fragment table in d_ws: 44 frags x 64 lanes x 8 bf16 (16 B)
#define F2_BASE 0           // conv2: 15 frags (mt 0..2, s 0..4)
#define F3_BASE 15          // conv3: 10 frags (mt 0..4, s 0..1)
#define F4_BASE 25          // conv4: 9  frags (mt 0..2, s 0..2)
#define F5_BASE 34          // conv5: 8  frags (mt 0..1, s 0..3)
#define F1_BASE 42          // conv1: 2  frags (mt 0..1), K=5 pad 32, pre-scaled by log2e
#define NFRAGS 44

typedef unsigned short u16;
typedef unsigned int u32;
typedef __attribute__((ext_vector_type(8))) short bf16x8;   // 8 bf16 = 4 VGPR
typedef __attribute__((ext_vector_type(4))) float f32x4;    // MFMA acc

__device__ __forceinline__ float exp2_f(float x) {
#if __has_builtin(__builtin_amdgcn_exp2f)
    return __builtin_amdgcn_exp2f(x);
#else
    float r; asm("v_exp_f32 %0, %1" : "=v"(r) : "v"(x)); return r;
#endif
}
// scaled-domain elu: y = x*log2e in, elu(x)*log2e out.
// neg branch: (e^x - 1)*log2e = 2^y*log2e - log2e -> one fma
__device__ __forceinline__ float eluc_f(float y) {
    float t = exp2_f(fminf(y, 0.0f));
    return fmaxf(y, fmaf(t, LOG2E, -LOG2E));
}
__device__ __forceinline__ float rcp_f(float x) {
    return __builtin_amdgcn_rcpf(x);
}
__device__ __forceinline__ float sq_f(float x) { return x * x; }
__device__ __forceinline__ u16 f2bf(float f) {              // RNE
    union { float f; u32 u; } v; v.f = f;
    u32 r = v.u + 0x7FFFu + ((v.u >> 16) & 1u);
    return (u16)(r >> 16);
}
__device__ __forceinline__ float bf2f(u16 h) {
    union { u32 u; float f; } v; v.u = ((u32)h) << 16;
    return v.f;
}
// pack two floats to bf16x2 by truncation: single v_perm_b32
__device__ __forceinline__ u32 pack_trunc(float a, float b) {
    union { float f; u32 u; } va, vb; va.f = a; vb.f = b;
#if __has_builtin(__builtin_amdgcn_perm)
    return __builtin_amdgcn_perm(vb.u, va.u, 0x07060302u);  // [a.b2,a.b3,b.b2,b.b3]
#else
    return (vb.u & 0xFFFF0000u) | (va.u >> 16);
#endif
}
__device__ __forceinline__ u32 pack_rne(float a, float b) {
    return (u32)f2bf(a) | ((u32)f2bf(b) << 16);
}

// ---- setup kernel: build all MFMA A-operand weight frags once per launch ----
__global__ __launch_bounds__(64) void build_frags_kernel(
    const float* __restrict__ w1, const float* __restrict__ w2,
    const float* __restrict__ w3, const float* __restrict__ w4,
    const float* __restrict__ w5, u16* __restrict__ ws)
{
    const int f = blockIdx.x;      // 0..43
    const int lane = threadIdx.x;  // 0..63
    const int m = lane & 15;
    const int q = lane >> 4;
    float wvv[8];
    #pragma unroll
    for (int j = 0; j < 8; ++j) wvv[j] = 0.0f;

    if (f < F3_BASE) {                       // conv2: 20->40 k=5, K-dim = dk*32+ic
        int mt = (f - F2_BASE) / 5, s = (f - F2_BASE) % 5;
        int oc = mt * 16 + m;
        #pragma unroll
        for (int j = 0; j < 8; ++j) {
            int ic = q * 8 + j;
            if (oc < 40 && ic < 20) wvv[j] = w2[oc * 100 + ic * 5 + s];
        }
    } else if (f < F4_BASE) {                // conv3: 40->80 k=1, K=40 pad 64
        int mt = (f - F3_BASE) / 2, s = (f - F3_BASE) % 2;
        int oc = mt * 16 + m;
        #pragma unroll
        for (int j = 0; j < 8; ++j) {
            int k = s * 32 + q * 8 + j;
            if (k < 40) wvv[j] = w3[oc * 40 + k];
        }
    } else if (f < F5_BASE) {                // conv4: 80->40 k=1, K=80 pad 96
        int mt = (f - F4_BASE) / 3, s = (f - F4_BASE) % 3;
        int oc = mt * 16 + m;
        #pragma unroll
        for (int j = 0; j < 8; ++j) {
            int k = s * 32 + q * 8 + j;
            if (oc < 40 && k < 80) wvv[j] = w4[oc * 80 + k];
        }
    } else if (f < F1_BASE) {                // conv5: 40->20 k=3, K=120: k=dk*40+ic
        int mt = (f - F5_BASE) / 4, s = (f - F5_BASE) % 4;
        int oc = mt * 16 + m;
        int k0 = s * 32 + q * 8;
        int dk = k0 / 40, ic0 = k0 - dk * 40;
        #pragma unroll
        for (int j = 0; j < 8; ++j) {
            if (oc < 20 && k0 < 120) wvv[j] = w5[oc * 120 + (ic0 + j) * 3 + dk];
        }
    } else {                                 // conv1: 1->20 k=5, K=5 pad 32 (x log2e)
        int mt = f - F1_BASE;                // 0..1
        int oc = mt * 16 + m;
        #pragma unroll
        for (int j = 0; j < 8; ++j) {
            int k = q * 8 + j;
            if (oc < 20 && k < 5) wvv[j] = w1[oc * 5 + k] * LOG2E;
        }
    }
    u32 pk[4];
    #pragma unroll
    for (int p = 0; p < 4; ++p)
        pk[p] = (u32)f2bf(wvv[2 * p]) | ((u32)f2bf(wvv[2 * p + 1]) << 16);
    u32* wp = (u32*)&ws[(f * 64 + lane) * 8];
    wp[0] = pk[0]; wp[1] = pk[1]; wp[2] = pk[2]; wp[3] = pk[3];
}

__device__ __forceinline__ bf16x8 ld_frag(const u16* ws, int f, int lane) {
    return *(const bf16x8*)&ws[(f * 64 + lane) * 8];
}

__global__ __launch_bounds__(NTHREADS, 2) void weno_nn_kernel(
    const float* __restrict__ uu, const float* __restrict__ e_ptr,
    const float* __restrict__ w1, const float* __restrict__ b1,
    const float* __restrict__ b2, const float* __restrict__ b3,
    const float* __restrict__ b4, const float* __restrict__ b5,
    const float* __restrict__ w6, const float* __restrict__ b6,
    const u16* __restrict__ wfr,
    float* __restrict__ out, int n_out, int N)
{
    __shared__ float s_uu[NUU];                         // 552 B
    __shared__ u32 s_difh[NDIFP];                       // 592 B packed (dif[d],dif[d+1]); beta overlays
    __shared__ __align__(16) u16 bufA[4 * WREG];        // 22528 B: per-wave x1(36x40) -> t3(32x88); later x5T(128x26)
    __shared__ __align__(16) u16 bufB[130 * 40];        // 10400 B: x2T(128x40) -> x4T(130x40)

    float* s_beta = (float*)s_difh;

    const int tid  = threadIdx.x;
    const int lane = tid & 63;
    const int wv_id = __builtin_amdgcn_readfirstlane(tid >> 6);  // 0..3
    const int m    = lane & 15;         // M/N index within frag
    const int q    = lane >> 4;         // quad, 0..3
    const int J0   = blockIdx.x * TOUT;
    const int P0   = J0 + 2;
    const int U0   = J0 - 4;

    u16* xw = &bufA[wv_id * WREG];      // wave-private region: x1 rows then t3 rows

    // ================= stage 0: uu tile =================
    for (int i = tid; i < NUU; i += NTHREADS) {
        int g = U0 + i;
        s_uu[i] = (g >= 0 && g < N) ? uu[g] : 0.0f;
    }
    __syncthreads();

    // ================= avg-diff -> packed bf16 pairs (dif[d], dif[d+1]) =================
    {
        auto difval = [&](int d) -> float {
            if (d >= NDIF) return 0.0f;
            int g = P0 - 5 + d;
            if (g < 0 || g >= N) return 0.0f;
            int j1 = g < N - 2 ? g : N - 2;
            int j0 = g - 1 > 0 ? g - 1 : 0;
            float dl = s_uu[j1 + 1 - U0] - s_uu[j1 - U0];
            float dr = s_uu[j0 + 1 - U0] - s_uu[j0 - U0];
            return 0.5f * (dl + dr);
        };
        for (int d = tid; d < NDIFP; d += NTHREADS)
            s_difh[d] = pack_rne(difval(d), difval(d + 1));
    }
    __syncthreads();

    // ======== FREE-RUN REGION: conv1 -> conv2 -> conv3 -> conv4, no barriers ========
    // Each wave computes its own x1 halo (36 rows) and keeps conv2/3/4 wave-local.
    // sched_barrier(0) pins per-phase codegen (prevents frag-load hoisting / VGPR blow-up).

    // ---- conv1 via MFMA: 1->20, k=5 (K pad 32), eluc -> wave-private x1 (36 rows) ----
    {
        bf16x8 a1[2];
        a1[0] = ld_frag(wfr, F1_BASE + 0, lane);
        a1[1] = ld_frag(wfr, F1_BASE + 1, lane);
        f32x4 bias1[2];
        #pragma unroll
        for (int r = 0; r < 4; ++r) {
            bias1[0][r] = b1[4 * q + r] * LOG2E;
            int oc = 16 + 4 * q + r;
            bias1[1][r] = (oc < 20) ? b1[oc] * LOG2E : 0.0f;
        }
        #pragma unroll
        for (int it = 0; it < 3; ++it) {             // 3 tiles cover 48 >= 36 rows
            const int li = it * 16 + m;              // local x1 row 0..47
            const int pos = wv_id * 32 + li;         // global x1 row (<= 143)
            bf16x8 bfrag;
            u32* bw = (u32*)&bfrag;
            bw[0] = s_difh[pos];                     // dif[pos], dif[pos+1]
            bw[1] = s_difh[pos + 2];                 // dif[pos+2], dif[pos+3]
            bw[2] = s_difh[pos + 4];                 // dif[pos+4], junk*0
            bw[3] = 0;
            f32x4 acc0 = bias1[0];
            f32x4 acc1 = bias1[1];
            acc0 = __builtin_amdgcn_mfma_f32_16x16x32_bf16(a1[0], bfrag, acc0, 0, 0, 0);
            acc1 = __builtin_amdgcn_mfma_f32_16x16x32_bf16(a1[1], bfrag, acc1, 0, 0, 0);
            if (li < 36) {                           // rows needed: conv2 reads li 0..35
                int g = P0 - 3 + pos;
                bool valid = (g >= 0 && g < N);
                float e0 = valid ? eluc_f(acc0[0]) : 0.0f;
                float e1 = valid ? eluc_f(acc0[1]) : 0.0f;
                float e2 = valid ? eluc_f(acc0[2]) : 0.0f;
                float e3 = valid ? eluc_f(acc0[3]) : 0.0f;
                u32* wp = (u32*)&xw[li * X1S + 4 * q];
                wp[0] = pack_trunc(e0, e1);
                wp[1] = pack_trunc(e2, e3);
                if (q == 0) {                        // oc 16..19
                    float f0 = valid ? eluc_f(acc1[0]) : 0.0f;
                    float f1 = valid ? eluc_f(acc1[1]) : 0.0f;
                    float f2 = valid ? eluc_f(acc1[2]) : 0.0f;
                    float f3 = valid ? eluc_f(acc1[3]) : 0.0f;
                    u32* wp2 = (u32*)&xw[li * X1S + 16];
                    wp2[0] = pack_trunc(f0, f1);
                    wp2[1] = pack_trunc(f2, f3);
                } else {                             // zero-pad cols 20..31
                    u32* wpz = (u32*)&xw[li * X1S + 20 + (q - 1) * 4];
                    wpz[0] = 0; wpz[1] = 0;
                }
            }
        }
    }
    __builtin_amdgcn_sched_barrier(0);

    // ---- conv2: 20->40, k=5 (im2col K=160), wave-local -> x2T rows in bufB ----
    {
        bf16x8 a2[3][5];
        #pragma unroll
        for (int mt = 0; mt < 3; ++mt)
            #pragma unroll
            for (int s = 0; s < 5; ++s)
                a2[mt][s] = ld_frag(wfr, F2_BASE + mt * 5 + s, lane);
        f32x4 bias2[3];
        #pragma unroll
        for (int mt = 0; mt < 3; ++mt) {
            #pragma unroll
            for (int r = 0; r < 4; ++r) {
                int oc = mt * 16 + 4 * q + r;
                bias2[mt][r] = (oc < 40) ? b2[oc] * LOG2E : 0.0f;
            }
        }
        for (int t = 0; t < 2; ++t) {
            const int lr = t * 16 + m;               // local row
            const int gr = wv_id * 32 + lr;          // global row
            f32x4 acc[3];
            #pragma unroll
            for (int mt = 0; mt < 3; ++mt) acc[mt] = bias2[mt];
            #pragma unroll
            for (int s = 0; s < 5; ++s) {
                bf16x8 bfrag = *(const bf16x8*)&xw[(lr + s) * X1S + q * 8];
                #pragma unroll
                for (int mt = 0; mt < 3; ++mt)
                    acc[mt] = __builtin_amdgcn_mfma_f32_16x16x32_bf16(a2[mt][s], bfrag, acc[mt], 0, 0, 0);
            }
            #pragma unroll
            for (int mt = 0; mt < 3; ++mt) {
                int oc0 = mt * 16 + 4 * q;
                if (oc0 < 40) {
                    u32* wp = (u32*)&bufB[gr * 40 + oc0];
                    wp[0] = pack_trunc(eluc_f(acc[mt][0]), eluc_f(acc[mt][1]));
                    wp[1] = pack_trunc(eluc_f(acc[mt][2]), eluc_f(acc[mt][3]));
                }
            }
        }
    }
    __builtin_amdgcn_sched_barrier(0);

    // ---- conv3: 40->80, k=1 (K=40 pad 64), wave-local -> t3 over own x1 region ----
    {
        bf16x8 a3[5][2];
        #pragma unroll
        for (int mt = 0; mt < 5; ++mt)
            #pragma unroll
            for (int s = 0; s < 2; ++s)
                a3[mt][s] = ld_frag(wfr, F3_BASE + mt * 2 + s, lane);
        f32x4 bias3[5];
        #pragma unroll
        for (int mt = 0; mt < 5; ++mt) {
            #pragma unroll
            for (int r = 0; r < 4; ++r) bias3[mt][r] = b3[mt * 16 + 4 * q + r] * LOG2E;
        }
        for (int t = 0; t < 2; ++t) {
            const int lr = t * 16 + m;
            const int gr = wv_id * 32 + lr;
            f32x4 acc[5];
            #pragma unroll
            for (int mt = 0; mt < 5; ++mt) acc[mt] = bias3[mt];
            // s=0: k 0..31
            {
                bf16x8 bfrag = *(const bf16x8*)&bufB[gr * 40 + q * 8];
                #pragma unroll
                for (int mt = 0; mt < 5; ++mt)
                    acc[mt] = __builtin_amdgcn_mfma_f32_16x16x32_bf16(a3[mt][0], bfrag, acc[mt], 0, 0, 0);
            }
            // s=1: only q==0 has valid k (32..39); other quads multiply zero A-weights
            {
                bf16x8 bfrag = *(const bf16x8*)&bufB[gr * 40 + ((q == 0) ? 32 : 0)];
                #pragma unroll
                for (int mt = 0; mt < 5; ++mt)
                    acc[mt] = __builtin_amdgcn_mfma_f32_16x16x32_bf16(a3[mt][1], bfrag, acc[mt], 0, 0, 0);
            }
            #pragma unroll
            for (int mt = 0; mt < 5; ++mt) {
                int oc0 = mt * 16 + 4 * q;           // 0..76
                u32* wp = (u32*)&xw[lr * T3S + oc0];
                wp[0] = pack_trunc(eluc_f(acc[mt][0]), eluc_f(acc[mt][1]));
                wp[1] = pack_trunc(eluc_f(acc[mt][2]), eluc_f(acc[mt][3]));
            }
        }
    }
    __builtin_amdgcn_sched_barrier(0);

    // ---- conv4: 80->40, k=1 (K=80 pad 96), wave-local -> x4T rows in bufB ----
    {
        bf16x8 a4[3][3];
        #pragma unroll
        for (int mt = 0; mt < 3; ++mt)
            #pragma unroll
            for (int s = 0; s < 3; ++s)
                a4[mt][s] = ld_frag(wfr, F4_BASE + mt * 3 + s, lane);
        f32x4 bias4[3];
        #pragma unroll
        for (int mt = 0; mt < 3; ++mt) {
            #pragma unroll
            for (int r = 0; r < 4; ++r) {
                int oc = mt * 16 + 4 * q + r;
                bias4[mt][r] = (oc < 40) ? b4[oc] * LOG2E : 0.0f;
            }
        }
        // zero-pad x4T rows 128,129 (conv5 right-edge halo; rows never hold x2)
        if (tid < 80) bufB[128 * 40 + tid] = 0;
        for (int t = 0; t < 2; ++t) {
            const int lr = t * 16 + m;
            const int gr = wv_id * 32 + lr;
            f32x4 acc[3];
            #pragma unroll
            for (int mt = 0; mt < 3; ++mt) acc[mt] = bias4[mt];
            #pragma unroll
            for (int s = 0; s < 3; ++s) {
                int k0 = s * 32 + q * 8;
                // k0 >= 80 lanes have zero A-weights; clamp address
                bf16x8 bfrag = *(const bf16x8*)&xw[lr * T3S + ((k0 < 80) ? k0 : 0)];
                #pragma unroll
                for (int mt = 0; mt < 3; ++mt)
                    acc[mt] = __builtin_amdgcn_mfma_f32_16x16x32_bf16(a4[mt][s], bfrag, acc[mt], 0, 0, 0);
            }
            #pragma unroll
            for (int mt = 0; mt < 3; ++mt) {
                int oc0 = mt * 16 + 4 * q;
                if (oc0 < 40) {
                    u32* wp = (u32*)&bufB[gr * 40 + oc0];
                    wp[0] = pack_trunc(eluc_f(acc[mt][0]), eluc_f(acc[mt][1]));
                    wp[1] = pack_trunc(eluc_f(acc[mt][2]), eluc_f(acc[mt][3]));
                }
            }
        }
    }
    __syncthreads();   // conv5 reads x4 cross-wave

    // ================= conv5: 40->20, k=3 (im2col K=120) -> x5T (bufA) =================
    {
        bf16x8 a5[2][4];
        #pragma unroll
        for (int mt = 0; mt < 2; ++mt)
            #pragma unroll
            for (int s = 0; s < 4; ++s)
                a5[mt][s] = ld_frag(wfr, F5_BASE + mt * 4 + s, lane);
        f32x4 bias5[2];
        #pragma unroll
        for (int mt = 0; mt < 2; ++mt) {
            #pragma unroll
            for (int r = 0; r < 4; ++r) {
                int oc = mt * 16 + 4 * q + r;
                bias5[mt][r] = (oc < 20) ? b5[oc] * LOG2E : 0.0f;
            }
        }
        for (int t = 0; t < 2; ++t) {
            const int N0 = (wv_id * 2 + t) * 16;
            f32x4 acc[2];
            #pragma unroll
            for (int mt = 0; mt < 2; ++mt) acc[mt] = bias5[mt];
            #pragma unroll
            for (int s = 0; s < 4; ++s) {
                int k0 = s * 32 + q * 8;
                int dk = (k0 < 120) ? (k0 / 40) : 0;
                int ic0 = (k0 < 120) ? (k0 - dk * 40) : 0;
                bf16x8 bfrag = *(const bf16x8*)&bufB[(N0 + m + dk) * 40 + ic0];
                #pragma unroll
                for (int mt = 0; mt < 2; ++mt)
                    acc[mt] = __builtin_amdgcn_mfma_f32_16x16x32_bf16(a5[mt][s], bfrag, acc[mt], 0, 0, 0);
            }
            #pragma unroll
            for (int mt = 0; mt < 2; ++mt) {
                int oc0 = mt * 16 + 4 * q;
                if (oc0 < 20) {
                    u32* wp = (u32*)&bufA[(N0 + m) * X5S + oc0];
                    wp[0] = pack_trunc(eluc_f(acc[mt][0]), eluc_f(acc[mt][1]));
                    wp[1] = pack_trunc(eluc_f(acc[mt][2]), eluc_f(acc[mt][3]));
                }
            }
        }
    }
    __syncthreads();

    // ===== conv6: 20->1, sigmoid + 0.1 -> beta (x5 carries x*log2e; raw w6 keeps =====
    // ===== the dot in exp2 domain: sigmoid(a) = 1/(1+2^-(a*log2e)) )            =====
    if (tid < NP) {
        float a = b6[0] * LOG2E;
        #pragma unroll
        for (int c = 0; c < 20; ++c)
            a += w6[c] * bf2f(bufA[tid * X5S + c]);
        s_beta[tid] = rcp_f(1.0f + exp2_f(-a)) + 0.1f;
    }
    __syncthreads();

    // ================= WENO5 =================
    const float eps = e_ptr[0];
    if (tid < TOUT) {
        int j = J0 + tid;
        if (j < n_out) {
            float a  = s_uu[tid + 5];
            float b  = s_uu[tid + 6];
            float c  = s_uu[tid + 7];
            float d  = s_uu[tid + 8];
            float ee = s_uu[tid + 9];
            float f  = s_uu[tid + 10];
            float m0 = s_beta[tid];
            float m1 = s_beta[tid + 1];
            float m2 = s_beta[tid + 2];

            const float i6 = 1.0f / 6.0f;
            float fp0 = (11.f * d - 7.f * ee + 2.f * f) * i6;
            float fp1 = (2.f * c + 5.f * d - ee) * i6;
            float fp2 = (-b + 5.f * c + 2.f * d) * i6;
            float fn0 = (11.f * c - 7.f * d + 2.f * ee) * i6;
            float fn1 = (2.f * b + 5.f * c - d) * i6;
            float fn2 = (-a + 5.f * b + 2.f * c) * i6;

            const float c1312 = 13.f / 12.f;
            float bp0 = c1312 * sq_f(d - 2.f * ee + f) + 0.25f * sq_f(3.f * d - 4.f * ee + f);
            float bp1 = c1312 * sq_f(c - 2.f * d + ee) + 0.25f * sq_f(c - ee);
            float bp2 = c1312 * sq_f(b - 2.f * c + d) + 0.25f * sq_f(b - 4.f * c + 3.f * d);
            float bn0 = c1312 * sq_f(c - 2.f * d + ee) + 0.25f * sq_f(3.f * c - 4.f * d + ee);
            float bn1 = c1312 * sq_f(b - 2.f * c + d) + 0.25f * sq_f(b - d);
            float bn2 = c1312 * sq_f(a - 2.f * b + c) + 0.25f * sq_f(a - 4.f * b + 3.f * c);

            bp0 *= m0; bp1 *= m1; bp2 *= m2;
            bn0 *= m0; bn1 *= m1; bn2 *= m2;

            float q0 = eps + bp0; q0 *= q0;
            float q1 = eps + bp1; q1 *= q1;
            float q2 = eps + bp2; q2 *= q2;
            float brs = bp2 - bp0; brs *= brs;
            float o0 = 0.1f * (1.f + brs * rcp_f(q0));
            float o1 = 0.6f * (1.f + brs * rcp_f(q1));
            float o2 = 0.3f * (1.f + brs * rcp_f(q2));
            float inv = rcp_f(o0 + o1 + o2);
            float fluxp = (o0 * fp0 + o1 * fp1 + o2 * fp2) * inv;

            q0 = eps + bn0; q0 *= q0;
            q1 = eps + bn1; q1 *= q1;
            q2 = eps + bn2; q2 *= q2;
            brs = bn2 - bn0; brs *= brs;
            o0 = 0.1f * (1.f + brs * rcp_f(q0));
            o1 = 0.6f * (1.f + brs * rcp_f(q1));
            o2 = 0.3f * (1.f + brs * rcp_f(q2));
            inv = rcp_f(o0 + o1 + o2);
            float fluxn = (o0 * fn0 + o1 * fn1 + o2 * fn2) * inv;

            out[j] = fluxp - fluxn;
        }
    }
}

extern "C" void kernel_launch(void* const* d_in, const int* in_sizes, int n_in,
                              void* d_out, int out_size, void* d_ws, size_t ws_size,
                              hipStream_t stream) {
    const float* uu = (const float*)d_in[0];
    const float* e  = (const float*)d_in[1];
    const float* w1 = (const float*)d_in[2];
    const float* b1 = (const float*)d_in[3];
    const float* w2 = (const float*)d_in[4];
    const float* b2 = (const float*)d_in[5];
    const float* w3 = (const float*)d_in[6];
    const float* b3 = (const float*)d_in[7];
    const float* w4 = (const float*)d_in[8];
    const float* b4 = (const float*)d_in[9];
    const float* w5 = (const float*)d_in[10];
    const float* b5 = (const float*)d_in[11];
    const float* w6 = (const float*)d_in[12];
    const float* b6 = (const float*)d_in[13];
    float* out = (float*)d_out;
    u16* wfr = (u16*)d_ws;
    const int N = in_sizes[0];
    const int nblocks = (out_size + TOUT - 1) / TOUT;

    build_frags_kernel<<<NFRAGS, 64, 0, stream>>>(w1, w2, w3, w4, w5, wfr);
    weno_nn_kernel<<<nblocks, NTHREADS, 0, stream>>>(
        uu, e, w1, b1, b2, b3, b4, b5, w6, b6, wfr,
        out, out_size, N);
}

// Round 10
// 257.170 us; speedup vs baseline: 1.1489x; 1.0680x over previous
//
#include <hip/hip_runtime.h>
#include <math.h>

#define NTHREADS 256
#define TOUT 126            // outputs per block
#define NP 128              // conv2/3/4/5 positions, base P0-1
#define X1S 40              // x1 row stride (u16) inside wave region, cols 20..31 zeroed
#define T3S 88              // t3 row stride (u16): 176B = 11x16B (odd) -> 2-way banks
#define X5S 26              // x5T stride: odd bank stride, conv6 conflict-free
#define NDIF 136            // real dif entries, base P0-5
#define NDIFP 152           // padded dif array (conv1-MFMA B reads up to 147)
#define NUU 138             // uu, base J0-4
#define WREG 2816           // u16 per wave-private region (5632 B = 32 rows x T3S)

// weight-fragment table in d_ws: 44 frags x 64 lanes x 8 bf16 (16 B)
#define F2_BASE 0           // conv2: 15 frags (mt 0..2, s 0..4)
#define F3_BASE 15          // conv3: 10 frags (mt 0..4, s 0..1)
#define F4_BASE 25          // conv4: 9  frags (mt 0..2, s 0..2)
#define F5_BASE 34          // conv5: 8  frags (mt 0..1, s 0..3)
#define F1_BASE 42          // conv1: 2  frags (mt 0..1), K=5 pad 32
#define NFRAGS 44

typedef unsigned short u16;
typedef unsigned int u32;
typedef __attribute__((ext_vector_type(8))) short bf16x8;   // 8 bf16 = 4 VGPR
typedef __attribute__((ext_vector_type(4))) float f32x4;    // MFMA acc

__device__ __forceinline__ float elu_f(float x) {
    return fmaxf(x, __expf(fminf(x, 0.0f)) - 1.0f);
}
__device__ __forceinline__ float rcp_f(float x) {
    return __builtin_amdgcn_rcpf(x);
}
__device__ __forceinline__ float sq_f(float x) { return x * x; }
__device__ __forceinline__ u16 f2bf(float f) {              // RNE
    union { float f; u32 u; } v; v.f = f;
    u32 r = v.u + 0x7FFFu + ((v.u >> 16) & 1u);
    return (u16)(r >> 16);
}
__device__ __forceinline__ float bf2f(u16 h) {
    union { u32 u; float f; } v; v.u = ((u32)h) << 16;
    return v.f;
}
// pack two floats to bf16x2 by truncation: single v_perm_b32
__device__ __forceinline__ u32 pack_trunc(float a, float b) {
    union { float f; u32 u; } va, vb; va.f = a; vb.f = b;
#if __has_builtin(__builtin_amdgcn_perm)
    return __builtin_amdgcn_perm(vb.u, va.u, 0x07060302u);  // [a.b2,a.b3,b.b2,b.b3]
#else
    return (vb.u & 0xFFFF0000u) | (va.u >> 16);
#endif
}
__device__ __forceinline__ u32 pack_rne(float a, float b) {
    return (u32)f2bf(a) | ((u32)f2bf(b) << 16);
}

// ---- setup kernel: build all MFMA A-operand weight frags once per launch ----
__global__ __launch_bounds__(64) void build_frags_kernel(
    const float* __restrict__ w1, const float* __restrict__ w2,
    const float* __restrict__ w3, const float* __restrict__ w4,
    const float* __restrict__ w5, u16* __restrict__ ws)
{
    const int f = blockIdx.x;      // 0..43
    const int lane = threadIdx.x;  // 0..63
    const int m = lane & 15;
    const int q = lane >> 4;
    float wvv[8];
    #pragma unroll
    for (int j = 0; j < 8; ++j) wvv[j] = 0.0f;

    if (f < F3_BASE) {                       // conv2: 20->40 k=5, K-dim = dk*32+ic
        int mt = (f - F2_BASE) / 5, s = (f - F2_BASE) % 5;
        int oc = mt * 16 + m;
        #pragma unroll
        for (int j = 0; j < 8; ++j) {
            int ic = q * 8 + j;
            if (oc < 40 && ic < 20) wvv[j] = w2[oc * 100 + ic * 5 + s];
        }
    } else if (f < F4_BASE) {                // conv3: 40->80 k=1, K=40 pad 64
        int mt = (f - F3_BASE) / 2, s = (f - F3_BASE) % 2;
        int oc = mt * 16 + m;
        #pragma unroll
        for (int j = 0; j < 8; ++j) {
            int k = s * 32 + q * 8 + j;
            if (k < 40) wvv[j] = w3[oc * 40 + k];
        }
    } else if (f < F5_BASE) {                // conv4: 80->40 k=1, K=80 pad 96
        int mt = (f - F4_BASE) / 3, s = (f - F4_BASE) % 3;
        int oc = mt * 16 + m;
        #pragma unroll
        for (int j = 0; j < 8; ++j) {
            int k = s * 32 + q * 8 + j;
            if (oc < 40 && k < 80) wvv[j] = w4[oc * 80 + k];
        }
    } else if (f < F1_BASE) {                // conv5: 40->20 k=3, K=120: k=dk*40+ic
        int mt = (f - F5_BASE) / 4, s = (f - F5_BASE) % 4;
        int oc = mt * 16 + m;
        int k0 = s * 32 + q * 8;
        int dk = k0 / 40, ic0 = k0 - dk * 40;
        #pragma unroll
        for (int j = 0; j < 8; ++j) {
            if (oc < 20 && k0 < 120) wvv[j] = w5[oc * 120 + (ic0 + j) * 3 + dk];
        }
    } else {                                 // conv1: 1->20 k=5, K=5 pad 32
        int mt = f - F1_BASE;                // 0..1
        int oc = mt * 16 + m;
        #pragma unroll
        for (int j = 0; j < 8; ++j) {
            int k = q * 8 + j;
            if (oc < 20 && k < 5) wvv[j] = w1[oc * 5 + k];
        }
    }
    u32 pk[4];
    #pragma unroll
    for (int p = 0; p < 4; ++p)
        pk[p] = (u32)f2bf(wvv[2 * p]) | ((u32)f2bf(wvv[2 * p + 1]) << 16);
    u32* wp = (u32*)&ws[(f * 64 + lane) * 8];
    wp[0] = pk[0]; wp[1] = pk[1]; wp[2] = pk[2]; wp[3] = pk[3];
}

__device__ __forceinline__ bf16x8 ld_frag(const u16* ws, int f, int lane) {
    return *(const bf16x8*)&ws[(f * 64 + lane) * 8];
}

__global__ __launch_bounds__(NTHREADS, 2) void weno_nn_kernel(
    const float* __restrict__ uu, const float* __restrict__ e_ptr,
    const float* __restrict__ w1, const float* __restrict__ b1,
    const float* __restrict__ b2, const float* __restrict__ b3,
    const float* __restrict__ b4, const float* __restrict__ b5,
    const float* __restrict__ w6, const float* __restrict__ b6,
    const u16* __restrict__ wfr,
    float* __restrict__ out, int n_out, int N)
{
    __shared__ float s_uu[NUU];                         // 552 B
    __shared__ float s_dif[NDIFP];                      // 608 B; f32[0..127] reused as beta
    __shared__ __align__(16) u16 bufA[4 * WREG];        // 22528 B: per-wave x1(36x40) -> t3(32x88); later x5T(128x26)
    __shared__ __align__(16) u16 bufB[130 * 40];        // 10400 B: x2T(128x40) -> x4T(130x40)

    float* s_beta = s_dif;

    const int tid  = threadIdx.x;
    const int lane = tid & 63;
    const int wv_id = __builtin_amdgcn_readfirstlane(tid >> 6);  // 0..3
    const int m    = lane & 15;         // M/N index within frag
    const int q    = lane >> 4;         // quad, 0..3
    const int J0   = blockIdx.x * TOUT;
    const int P0   = J0 + 2;
    const int U0   = J0 - 4;

    u16* xw = &bufA[wv_id * WREG];      // wave-private region: x1 rows then t3 rows

    // ================= stage 0: uu tile =================
    for (int i = tid; i < NUU; i += NTHREADS) {
        int g = U0 + i;
        s_uu[i] = (g >= 0 && g < N) ? uu[g] : 0.0f;
    }
    __syncthreads();

    // ================= avg-diff (padded to NDIFP with zeros) =================
    for (int d = tid; d < NDIFP; d += NTHREADS) {
        int g = P0 - 5 + d;
        float v = 0.0f;
        if (d < NDIF && g >= 0 && g < N) {
            int j1 = g < N - 2 ? g : N - 2;
            int j0 = g - 1 > 0 ? g - 1 : 0;
            float dl = s_uu[j1 + 1 - U0] - s_uu[j1 - U0];
            float dr = s_uu[j0 + 1 - U0] - s_uu[j0 - U0];
            v = 0.5f * (dl + dr);
        }
        s_dif[d] = v;
    }
    __syncthreads();

    // ======== FREE-RUN REGION: conv1 -> conv2 -> conv3 -> conv4, no barriers ========
    // Each wave computes its own x1 halo (36 rows) and keeps conv2/3/4 wave-local.
    // sched_barrier(0) pins per-phase codegen (prevents frag-load hoisting / VGPR blow-up).

    // ---- conv1 via MFMA: 1->20, k=5 (K pad 32), elu -> wave-private x1 (36 rows) ----
    {
        bf16x8 a1[2];
        a1[0] = ld_frag(wfr, F1_BASE + 0, lane);
        a1[1] = ld_frag(wfr, F1_BASE + 1, lane);
        f32x4 bias1[2];
        #pragma unroll
        for (int r = 0; r < 4; ++r) {
            bias1[0][r] = b1[4 * q + r];
            int oc = 16 + 4 * q + r;
            bias1[1][r] = (oc < 20) ? b1[oc] : 0.0f;
        }
        #pragma unroll
        for (int it = 0; it < 3; ++it) {             // 3 tiles cover 48 >= 36 rows
            const int li = it * 16 + m;              // local x1 row 0..47
            const int pos = wv_id * 32 + li;         // global x1 row (<= 143)
            float d0 = s_dif[pos + 0];
            float d1 = s_dif[pos + 1];
            float d2 = s_dif[pos + 2];
            float d3 = s_dif[pos + 3];
            float d4 = s_dif[pos + 4];
            bf16x8 bfrag;
            u32* bw = (u32*)&bfrag;
            bw[0] = pack_rne(d0, d1);
            bw[1] = pack_rne(d2, d3);
            bw[2] = pack_rne(d4, 0.0f);
            bw[3] = 0;
            f32x4 acc0 = bias1[0];
            f32x4 acc1 = bias1[1];
            acc0 = __builtin_amdgcn_mfma_f32_16x16x32_bf16(a1[0], bfrag, acc0, 0, 0, 0);
            acc1 = __builtin_amdgcn_mfma_f32_16x16x32_bf16(a1[1], bfrag, acc1, 0, 0, 0);
            if (li < 36) {                           // rows needed: conv2 reads li 0..35
                int g = P0 - 3 + pos;
                bool valid = (g >= 0 && g < N);
                float e0 = valid ? elu_f(acc0[0]) : 0.0f;
                float e1 = valid ? elu_f(acc0[1]) : 0.0f;
                float e2 = valid ? elu_f(acc0[2]) : 0.0f;
                float e3 = valid ? elu_f(acc0[3]) : 0.0f;
                u32* wp = (u32*)&xw[li * X1S + 4 * q];
                wp[0] = pack_trunc(e0, e1);
                wp[1] = pack_trunc(e2, e3);
                if (q == 0) {                        // oc 16..19
                    float f0 = valid ? elu_f(acc1[0]) : 0.0f;
                    float f1 = valid ? elu_f(acc1[1]) : 0.0f;
                    float f2 = valid ? elu_f(acc1[2]) : 0.0f;
                    float f3 = valid ? elu_f(acc1[3]) : 0.0f;
                    u32* wp2 = (u32*)&xw[li * X1S + 16];
                    wp2[0] = pack_trunc(f0, f1);
                    wp2[1] = pack_trunc(f2, f3);
                } else {                             // zero-pad cols 20..31
                    u32* wpz = (u32*)&xw[li * X1S + 20 + (q - 1) * 4];
                    wpz[0] = 0; wpz[1] = 0;
                }
            }
        }
    }
    __builtin_amdgcn_sched_barrier(0);

    // ---- conv2: 20->40, k=5 (im2col K=160), wave-local -> x2T rows in bufB ----
    {
        bf16x8 a2[3][5];
        #pragma unroll
        for (int mt = 0; mt < 3; ++mt)
            #pragma unroll
            for (int s = 0; s < 5; ++s)
                a2[mt][s] = ld_frag(wfr, F2_BASE + mt * 5 + s, lane);
        f32x4 bias2[3];
        #pragma unroll
        for (int mt = 0; mt < 3; ++mt) {
            #pragma unroll
            for (int r = 0; r < 4; ++r) {
                int oc = mt * 16 + 4 * q + r;
                bias2[mt][r] = (oc < 40) ? b2[oc] : 0.0f;
            }
        }
        for (int t = 0; t < 2; ++t) {
            const int lr = t * 16 + m;               // local row
            const int gr = wv_id * 32 + lr;          // global row
            f32x4 acc[3];
            #pragma unroll
            for (int mt = 0; mt < 3; ++mt) acc[mt] = bias2[mt];
            #pragma unroll
            for (int s = 0; s < 5; ++s) {
                bf16x8 bfrag = *(const bf16x8*)&xw[(lr + s) * X1S + q * 8];
                #pragma unroll
                for (int mt = 0; mt < 3; ++mt)
                    acc[mt] = __builtin_amdgcn_mfma_f32_16x16x32_bf16(a2[mt][s], bfrag, acc[mt], 0, 0, 0);
            }
            #pragma unroll
            for (int mt = 0; mt < 3; ++mt) {
                int oc0 = mt * 16 + 4 * q;
                if (oc0 < 40) {
                    u32* wp = (u32*)&bufB[gr * 40 + oc0];
                    wp[0] = pack_trunc(elu_f(acc[mt][0]), elu_f(acc[mt][1]));
                    wp[1] = pack_trunc(elu_f(acc[mt][2]), elu_f(acc[mt][3]));
                }
            }
        }
    }
    __builtin_amdgcn_sched_barrier(0);

    // ---- conv3: 40->80, k=1 (K=40 pad 64), wave-local -> t3 over own x1 region ----
    {
        bf16x8 a3[5][2];
        #pragma unroll
        for (int mt = 0; mt < 5; ++mt)
            #pragma unroll
            for (int s = 0; s < 2; ++s)
                a3[mt][s] = ld_frag(wfr, F3_BASE + mt * 2 + s, lane);
        f32x4 bias3[5];
        #pragma unroll
        for (int mt = 0; mt < 5; ++mt) {
            #pragma unroll
            for (int r = 0; r < 4; ++r) bias3[mt][r] = b3[mt * 16 + 4 * q + r];
        }
        for (int t = 0; t < 2; ++t) {
            const int lr = t * 16 + m;
            const int gr = wv_id * 32 + lr;
            f32x4 acc[5];
            #pragma unroll
            for (int mt = 0; mt < 5; ++mt) acc[mt] = bias3[mt];
            // s=0: k 0..31
            {
                bf16x8 bfrag = *(const bf16x8*)&bufB[gr * 40 + q * 8];
                #pragma unroll
                for (int mt = 0; mt < 5; ++mt)
                    acc[mt] = __builtin_amdgcn_mfma_f32_16x16x32_bf16(a3[mt][0], bfrag, acc[mt], 0, 0, 0);
            }
            // s=1: only q==0 has valid k (32..39); other quads multiply zero A-weights
            {
                bf16x8 bfrag = *(const bf16x8*)&bufB[gr * 40 + ((q == 0) ? 32 : 0)];
                #pragma unroll
                for (int mt = 0; mt < 5; ++mt)
                    acc[mt] = __builtin_amdgcn_mfma_f32_16x16x32_bf16(a3[mt][1], bfrag, acc[mt], 0, 0, 0);
            }
            #pragma unroll
            for (int mt = 0; mt < 5; ++mt) {
                int oc0 = mt * 16 + 4 * q;           // 0..76
                u32* wp = (u32*)&xw[lr * T3S + oc0];
                wp[0] = pack_trunc(elu_f(acc[mt][0]), elu_f(acc[mt][1]));
                wp[1] = pack_trunc(elu_f(acc[mt][2]), elu_f(acc[mt][3]));
            }
        }
    }
    __builtin_amdgcn_sched_barrier(0);

    // ---- conv4: 80->40, k=1 (K=80 pad 96), wave-local -> x4T rows in bufB ----
    {
        bf16x8 a4[3][3];
        #pragma unroll
        for (int mt = 0; mt < 3; ++mt)
            #pragma unroll
            for (int s = 0; s < 3; ++s)
                a4[mt][s] = ld_frag(wfr, F4_BASE + mt * 3 + s, lane);
        f32x4 bias4[3];
        #pragma unroll
        for (int mt = 0; mt < 3; ++mt) {
            #pragma unroll
            for (int r = 0; r < 4; ++r) {
                int oc = mt * 16 + 4 * q + r;
                bias4[mt][r] = (oc < 40) ? b4[oc] : 0.0f;
            }
        }
        // zero-pad x4T rows 128,129 (conv5 right-edge halo; rows never hold x2)
        if (tid < 80) bufB[128 * 40 + tid] = 0;
        for (int t = 0; t < 2; ++t) {
            const int lr = t * 16 + m;
            const int gr = wv_id * 32 + lr;
            f32x4 acc[3];
            #pragma unroll
            for (int mt = 0; mt < 3; ++mt) acc[mt] = bias4[mt];
            #pragma unroll
            for (int s = 0; s < 3; ++s) {
                int k0 = s * 32 + q * 8;
                // k0 >= 80 lanes have zero A-weights; clamp address
                bf16x8 bfrag = *(const bf16x8*)&xw[lr * T3S + ((k0 < 80) ? k0 : 0)];
                #pragma unroll
                for (int mt = 0; mt < 3; ++mt)
                    acc[mt] = __builtin_amdgcn_mfma_f32_16x16x32_bf16(a4[mt][s], bfrag, acc[mt], 0, 0, 0);
            }
            #pragma unroll
            for (int mt = 0; mt < 3; ++mt) {
                int oc0 = mt * 16 + 4 * q;
                if (oc0 < 40) {
                    u32* wp = (u32*)&bufB[gr * 40 + oc0];
                    wp[0] = pack_trunc(elu_f(acc[mt][0]), elu_f(acc[mt][1]));
                    wp[1] = pack_trunc(elu_f(acc[mt][2]), elu_f(acc[mt][3]));
                }
            }
        }
    }
    __syncthreads();   // conv5 reads x4 cross-wave

    // ================= conv5: 40->20, k=3 (im2col K=120) -> x5T (bufA) =================
    {
        bf16x8 a5[2][4];
        #pragma unroll
        for (int mt = 0; mt < 2; ++mt)
            #pragma unroll
            for (int s = 0; s < 4; ++s)
                a5[mt][s] = ld_frag(wfr, F5_BASE + mt * 4 + s, lane);
        f32x4 bias5[2];
        #pragma unroll
        for (int mt = 0; mt < 2; ++mt) {
            #pragma unroll
            for (int r = 0; r < 4; ++r) {
                int oc = mt * 16 + 4 * q + r;
                bias5[mt][r] = (oc < 20) ? b5[oc] : 0.0f;
            }
        }
        for (int t = 0; t < 2; ++t) {
            const int N0 = (wv_id * 2 + t) * 16;
            f32x4 acc[2];
            #pragma unroll
            for (int mt = 0; mt < 2; ++mt) acc[mt] = bias5[mt];
            #pragma unroll
            for (int s = 0; s < 4; ++s) {
                int k0 = s * 32 + q * 8;
                int dk = (k0 < 120) ? (k0 / 40) : 0;
                int ic0 = (k0 < 120) ? (k0 - dk * 40) : 0;
                bf16x8 bfrag = *(const bf16x8*)&bufB[(N0 + m + dk) * 40 + ic0];
                #pragma unroll
                for (int mt = 0; mt < 2; ++mt)
                    acc[mt] = __builtin_amdgcn_mfma_f32_16x16x32_bf16(a5[mt][s], bfrag, acc[mt], 0, 0, 0);
            }
            #pragma unroll
            for (int mt = 0; mt < 2; ++mt) {
                int oc0 = mt * 16 + 4 * q;
                if (oc0 < 20) {
                    u32* wp = (u32*)&bufA[(N0 + m) * X5S + oc0];
                    wp[0] = pack_trunc(elu_f(acc[mt][0]), elu_f(acc[mt][1]));
                    wp[1] = pack_trunc(elu_f(acc[mt][2]), elu_f(acc[mt][3]));
                }
            }
        }
    }
    __syncthreads();

    // ================= conv6: 20->1, sigmoid + 0.1 -> beta (reuse s_dif) =================
    if (tid < NP) {
        float a = b6[0];
        #pragma unroll
        for (int c = 0; c < 20; ++c)
            a += w6[c] * bf2f(bufA[tid * X5S + c]);
        s_beta[tid] = rcp_f(1.0f + __expf(-a)) + 0.1f;
    }
    __syncthreads();

    // ================= WENO5 =================
    const float eps = e_ptr[0];
    if (tid < TOUT) {
        int j = J0 + tid;
        if (j < n_out) {
            float a  = s_uu[tid + 5];
            float b  = s_uu[tid + 6];
            float c  = s_uu[tid + 7];
            float d  = s_uu[tid + 8];
            float ee = s_uu[tid + 9];
            float f  = s_uu[tid + 10];
            float m0 = s_beta[tid];
            float m1 = s_beta[tid + 1];
            float m2 = s_beta[tid + 2];

            const float i6 = 1.0f / 6.0f;
            float fp0 = (11.f * d - 7.f * ee + 2.f * f) * i6;
            float fp1 = (2.f * c + 5.f * d - ee) * i6;
            float fp2 = (-b + 5.f * c + 2.f * d) * i6;
            float fn0 = (11.f * c - 7.f * d + 2.f * ee) * i6;
            float fn1 = (2.f * b + 5.f * c - d) * i6;
            float fn2 = (-a + 5.f * b + 2.f * c) * i6;

            const float c1312 = 13.f / 12.f;
            float bp0 = c1312 * sq_f(d - 2.f * ee + f) + 0.25f * sq_f(3.f * d - 4.f * ee + f);
            float bp1 = c1312 * sq_f(c - 2.f * d + ee) + 0.25f * sq_f(c - ee);
            float bp2 = c1312 * sq_f(b - 2.f * c + d) + 0.25f * sq_f(b - 4.f * c + 3.f * d);
            float bn0 = c1312 * sq_f(c - 2.f * d + ee) + 0.25f * sq_f(3.f * c - 4.f * d + ee);
            float bn1 = c1312 * sq_f(b - 2.f * c + d) + 0.25f * sq_f(b - d);
            float bn2 = c1312 * sq_f(a - 2.f * b + c) + 0.25f * sq_f(a - 4.f * b + 3.f * c);

            bp0 *= m0; bp1 *= m1; bp2 *= m2;
            bn0 *= m0; bn1 *= m1; bn2 *= m2;

            float q0 = eps + bp0; q0 *= q0;
            float q1 = eps + bp1; q1 *= q1;
            float q2 = eps + bp2; q2 *= q2;
            float brs = bp2 - bp0; brs *= brs;
            float o0 = 0.1f * (1.f + brs * rcp_f(q0));
            float o1 = 0.6f * (1.f + brs * rcp_f(q1));
            float o2 = 0.3f * (1.f + brs * rcp_f(q2));
            float inv = rcp_f(o0 + o1 + o2);
            float fluxp = (o0 * fp0 + o1 * fp1 + o2 * fp2) * inv;

            q0 = eps + bn0; q0 *= q0;
            q1 = eps + bn1; q1 *= q1;
            q2 = eps + bn2; q2 *= q2;
            brs = bn2 - bn0; brs *= brs;
            o0 = 0.1f * (1.f + brs * rcp_f(q0));
            o1 = 0.6f * (1.f + brs * rcp_f(q1));
            o2 = 0.3f * (1.f + brs * rcp_f(q2));
            inv = rcp_f(o0 + o1 + o2);
            float fluxn = (o0 * fn0 + o1 * fn1 + o2 * fn2) * inv;

            out[j] = fluxp - fluxn;
        }
    }
}

extern "C" void kernel_launch(void* const* d_in, const int* in_sizes, int n_in,
                              void* d_out, int out_size, void* d_ws, size_t ws_size,
                              hipStream_t stream) {
    const float* uu = (const float*)d_in[0];
    const float* e  = (const float*)d_in[1];
    const float* w1 = (const float*)d_in[2];
    const float* b1 = (const float*)d_in[3];
    const float* w2 = (const float*)d_in[4];
    const float* b2 = (const float*)d_in[5];
    const float* w3 = (const float*)d_in[6];
    const float* b3 = (const float*)d_in[7];
    const float* w4 = (const float*)d_in[8];
    const float* b4 = (const float*)d_in[9];
    const float* w5 = (const float*)d_in[10];
    const float* b5 = (const float*)d_in[11];
    const float* w6 = (const float*)d_in[12];
    const float* b6 = (const float*)d_in[13];
    float* out = (float*)d_out;
    u16* wfr = (u16*)d_ws;
    const int N = in_sizes[0];
    const int nblocks = (out_size + TOUT - 1) / TOUT;

    build_frags_kernel<<<NFRAGS, 64, 0, stream>>>(w1, w2, w3, w4, w5, wfr);
    weno_nn_kernel<<<nblocks, NTHREADS, 0, stream>>>(
        uu, e, w1, b1, b2, b3, b4, b5, w6, b6, wfr,
        out, out_size, N);
}